// Round 9
// baseline (4893.324 us; speedup 1.0000x reference)
//
#include <hip/hip_runtime.h>
#include <math.h>

#define VOCAB 10000
#define VPAD  10240   // padded so fc n-tile -> XCD map is stable (bid%8)
#define EMBED 256
#define ENC   2048
#define DEC   512
#define ATT   512
#define B_    64
#define P_    49
#define T_    30
#define G4    2048   // 4*DEC
#define KH1   10     // g1 split-K chunks (8 over ctx K=2048, 2 over h1 K=512)
#define SL    32768  // one state slice = B_*DEC

typedef __bf16 bf16_t;
typedef bf16_t bf16x8 __attribute__((ext_vector_type(8)));
typedef float  f32x4  __attribute__((ext_vector_type(4)));

__device__ __forceinline__ float sigf(float x) { return 1.f / (1.f + expf(-x)); }

// ---------------------------------------------------------------------------
// Inter-block barrier (co-resident grid only). Writer side publishes with an
// agent-scope fence + device-scope atomicAdd; waiter spins on the counter and
// fences before touching produced data. Counters are per-step slots zeroed by
// prep_k on EVERY call (graph-replay safe).
// ---------------------------------------------------------------------------
__device__ __forceinline__ void bar_arrive(int* cnt)
{
    __syncthreads();
    __threadfence();
    if (threadIdx.x == 0) atomicAdd(cnt, 1);
}
__device__ __forceinline__ void bar_wait(int* cnt, int target)
{
    if (threadIdx.x == 0) {
        while (atomicAdd(cnt, 0) < target) __builtin_amdgcn_s_sleep(2);
    }
    __syncthreads();
    __threadfence();
}

// ---------------------------------------------------------------------------
// One-time prep: state zeroing, barrier-counter zeroing, hwb(t=0)=b2 rows,
// bias sums, bf16 conversions, MFMA-fragment weight packings (verified r5-r8):
// fp1[((nb*80+kf)*4+s)*512+l*8+j] = Wcat1[s*512+nb*16+(l&15)][kf*32+(l>>4)*8+j]
// fp2 same with 32 kf. W2p: 16-col strips of W2.
// ---------------------------------------------------------------------------
__global__ void prep_k(
    const float* __restrict__ b_ih1, const float* __restrict__ b_hh1, float* __restrict__ bsum1,
    const float* __restrict__ b_ih2, const float* __restrict__ b_hh2, float* __restrict__ bsum2,
    const float* __restrict__ W2,    bf16_t* __restrict__ W2p,
    const float* __restrict__ W1,    bf16_t* __restrict__ W1b,
    const float* __restrict__ W_ih1, bf16_t* __restrict__ Wihel, bf16_t* __restrict__ fp1,
    const float* __restrict__ W_ih2, const float* __restrict__ W_hh1,
    const float* __restrict__ W_hh2, bf16_t* __restrict__ fp2,
    const float* __restrict__ fc_W,  bf16_t* __restrict__ fcWb,
    const float* __restrict__ features, bf16_t* __restrict__ featb,
    const int* __restrict__ caps, const float* __restrict__ emb, bf16_t* __restrict__ xgb,
    const float* __restrict__ b2, float* __restrict__ hwb,
    bf16_t* __restrict__ h1s0, bf16_t* __restrict__ h2s0,
    float* __restrict__ c1s0, float* __restrict__ c2s0, int* __restrict__ cnt)
{
    long stride = (long)gridDim.x * blockDim.x;
    long i0 = (long)blockIdx.x * blockDim.x + threadIdx.x;
    for (long i = i0; i < T_ * 4; i += stride) cnt[i] = 0;
    for (long i = i0; i < SL; i += stride) {
        h1s0[i] = (bf16_t)0.f; h2s0[i] = (bf16_t)0.f;
        c1s0[i] = 0.f; c2s0[i] = 0.f;
        hwb[i] = b2[i & 511];          // hw(t=0) = 0 @ W2^T + b2
    }
    for (long i = i0; i < 2048; i += stride) {
        bsum1[i] = b_ih1[i] + b_hh1[i];
        bsum2[i] = b_ih2[i] + b_hh2[i];
    }
    for (long i = i0; i < 512L * 512; i += stride) {   // W2p fragment pack
        long j8 = i & 7, lq = (i >> 3) & 63, kf = (i >> 9) & 15, nt = i >> 13;
        W2p[i] = (bf16_t)W2[(nt * 16 + (lq & 15)) * 512 + kf * 32 + (lq >> 4) * 8 + j8];
    }
    for (long i = i0; i < 512L * 2048; i += stride) W1b[i] = (bf16_t)W1[i];
    for (long i = i0; i < 2048L * 256; i += stride) {
        long j = i >> 8, c = i & 255;
        Wihel[i] = (bf16_t)W_ih1[j * 2304 + c];
    }
    for (long i = i0; i < 2048L * 2560; i += stride) { // fp1
        long j8 = i & 7, lq = (i >> 3) & 63, s = (i >> 9) & 3, nk = i >> 11;
        long kf = nk % 80, nb = nk / 80;
        long c = s * 512 + nb * 16 + (lq & 15);
        long k = kf * 32 + (lq >> 4) * 8 + j8;
        fp1[i] = (bf16_t)(k < 2048 ? W_ih1[c * 2304 + 256 + k] : W_hh1[c * 512 + (k - 2048)]);
    }
    for (long i = i0; i < 2048L * 1024; i += stride) { // fp2
        long j8 = i & 7, lq = (i >> 3) & 63, s = (i >> 9) & 3, nk = i >> 11;
        long kf = nk & 31, nb = nk >> 5;
        long c = s * 512 + nb * 16 + (lq & 15);
        long k = kf * 32 + (lq >> 4) * 8 + j8;
        fp2[i] = (bf16_t)(k < 512 ? W_ih2[c * 512 + k] : W_hh2[c * 512 + (k - 512)]);
    }
    for (long i = i0; i < (long)VPAD * 512; i += stride) {
        long r = i >> 9;
        fcWb[i] = (bf16_t)(r < VOCAB ? fc_W[i] : 0.f);
    }
    for (long i = i0; i < 3136L * 2048; i += stride) featb[i] = (bf16_t)features[i];
    for (long i = i0; i < 1920L * 256; i += stride) {
        long row = i >> 8, e = i & 255;
        long tq = row >> 6, b = row & 63;
        int cap = caps[b * T_ + tq];
        xgb[i] = (bf16_t)emb[(long)cap * 256 + e];
    }
}

// ---------------------------------------------------------------------------
// bf16 MFMA GEMM (bulk GEMMs) — verified r2/r6/r7/r8.
// ---------------------------------------------------------------------------
template <int MODE>
__global__ __launch_bounds__(256) void mm_bf16(
    const bf16_t* __restrict__ A, int lda,
    const bf16_t* __restrict__ Bw, int ldb,
    const float* __restrict__ bias,
    float* __restrict__ outF, bf16_t* __restrict__ outB, int ldo,
    int N, int K)
{
    __shared__ bf16_t Apad[64][72];
    __shared__ bf16_t Bpad[64][72];
    const int bn = blockIdx.x * 64, bm = blockIdx.y * 64;
    const int tid = threadIdx.x;
    const int w = tid >> 6, l = tid & 63;
    f32x4 acc[4] = {};

    for (int k0 = 0; k0 < K; k0 += 64) {
        for (int c = tid; c < 512; c += 256) {
            int row = c >> 3, q = c & 7;
            *(bf16x8*)&Apad[row][q * 8] = *(const bf16x8*)&A[(size_t)(bm + row) * lda + k0 + q * 8];
            *(bf16x8*)&Bpad[row][q * 8] = *(const bf16x8*)&Bw[(size_t)(bn + row) * ldb + k0 + q * 8];
        }
        __syncthreads();
#pragma unroll
        for (int ks = 0; ks < 2; ++ks) {
            bf16x8 a8 = *(const bf16x8*)&Apad[w * 16 + (l & 15)][ks * 32 + (l >> 4) * 8];
#pragma unroll
            for (int nf = 0; nf < 4; ++nf) {
                bf16x8 b8 = *(const bf16x8*)&Bpad[nf * 16 + (l & 15)][ks * 32 + (l >> 4) * 8];
                acc[nf] = __builtin_amdgcn_mfma_f32_16x16x32_bf16(a8, b8, acc[nf], 0, 0, 0);
            }
        }
        __syncthreads();
    }

    int rbase = bm + w * 16 + (l >> 4) * 4;
    int cl = l & 15;
#pragma unroll
    for (int nf = 0; nf < 4; ++nf) {
        int col = bn + nf * 16 + cl;
#pragma unroll
        for (int j = 0; j < 4; ++j) {
            int row = rbase + j;
            float v = acc[nf][j];
            if (MODE == 0) {
                outB[(size_t)row * ldo + col] = (bf16_t)(v + bias[col]);
            } else {
                if (col < N) {
                    int orow = (row & 63) * T_ + (row >> 6);  // t*64+b -> b*T+t
                    outF[(size_t)orow * ldo + col] = v + bias[col];
                }
            }
        }
    }
}

// ===========================================================================
// ONE KERNEL PER STEP: 320 blocks x 256 threads, 4 in-kernel barriers.
// All phase bodies are r7/r8-hardware-verified code:
//  A (bid<64)     attn: scores+softmax+ctx (reads hwb of this t)   -> ctxb
//  B (all 320)    g1 split-K partials (nb=bid&31, kh=bid>>5)       -> G1p
//  C (bid<128)    pw1: sum partials + xembb, LSTM1                 -> h1(t+1)
//  D (128..159)   g2 full-K + LSTM2 (nb=bid-128)                   -> h2(t+1)
//  E (same 32)    hw(t+1) = h2(t+1) @ W2^T + b2                    -> hwb
// Co-residency: 320 blocks of 256 thr / 512B LDS on 256 CUs is trivially
// resident (>= 8 blocks/CU capacity), so spin-barriers cannot deadlock.
// ===========================================================================
struct SP {
    const bf16_t *featb, *fW1b, *W2p, *fp1, *fp2, *xembb;
    const float *V, *bV, *b2, *bsum2;
    bf16_t *ctxb, *h1s, *h2s;
    float *hwb, *G1p, *c1s, *c2s;
    int *cnt;
};

__global__ __launch_bounds__(256) void step_k(SP p, int t)
{
    const int bid = blockIdx.x;
    const int tid = threadIdx.x;
    const int w = tid >> 6, l = tid & 63;
    __shared__ float sc[64];
    __shared__ float wn[64];

    int* cA = p.cnt + t * 4 + 0;   // target 64
    int* cB = p.cnt + t * 4 + 1;   // target 320
    int* cC = p.cnt + t * 4 + 2;   // target 128
    int* cD = p.cnt + t * 4 + 3;   // target 32

    const bf16_t* h1r = p.h1s + (size_t)t * SL;
    bf16_t* h1w = p.h1s + (size_t)(t + 1) * SL;
    const bf16_t* h2r = p.h2s + (size_t)t * SL;
    bf16_t* h2w = p.h2s + (size_t)(t + 1) * SL;
    const float* c1r = p.c1s + (size_t)(t & 1) * SL;
    float* c1w = p.c1s + (size_t)((t + 1) & 1) * SL;
    const float* c2r = p.c2s + (size_t)(t & 1) * SL;
    float* c2w = p.c2s + (size_t)((t + 1) & 1) * SL;

    // ---------------- A: attention ----------------
    if (bid < 64) {
        const int b = bid;
        {
            float hwr[8], Vr[8];
#pragma unroll
            for (int i = 0; i < 8; ++i) { hwr[i] = p.hwb[b * 512 + l * 8 + i]; Vr[i] = p.V[l * 8 + i]; }
            for (int pq = w; pq < P_; pq += 4) {
                bf16x8 f8 = *(const bf16x8*)&p.fW1b[(size_t)(b * P_ + pq) * 512 + l * 8];
                float s = 0.f;
#pragma unroll
                for (int i = 0; i < 8; ++i) s += tanhf((float)f8[i] + hwr[i]) * Vr[i];
#pragma unroll
                for (int o = 32; o; o >>= 1) s += __shfl_xor(s, o);
                if (l == 0) sc[pq] = s + p.bV[0];
            }
        }
        __syncthreads();
        {
            float m = -1e30f;
            for (int q = 0; q < P_; ++q) m = fmaxf(m, sc[q]);
            float ss = 0.f;
            for (int q = 0; q < P_; ++q) ss += expf(sc[q] - m);
            if (tid < P_) wn[tid] = expf(sc[tid] - m) / ss;
        }
        __syncthreads();
        {
            float acc[8] = {};
            const bf16_t* fb = p.featb + (size_t)b * P_ * 2048 + tid * 8;
#pragma unroll 7
            for (int q = 0; q < P_; ++q) {
                bf16x8 f8 = *(const bf16x8*)&fb[(size_t)q * 2048];
                float wq = wn[q];
#pragma unroll
                for (int i = 0; i < 8; ++i) acc[i] += wq * (float)f8[i];
            }
            bf16x8 o8;
#pragma unroll
            for (int i = 0; i < 8; ++i) o8[i] = (bf16_t)acc[i];
            *(bf16x8*)&p.ctxb[b * 2048 + tid * 8] = o8;
        }
        bar_arrive(cA);
    }
    bar_wait(cA, 64);

    // ---------------- B: gates1 split-K partials ----------------
    {
        const int nb = bid & 31, kh = bid >> 5;
        const int arow = w * 16 + (l & 15);
        const int koff = (l >> 4) * 8;
        const bf16_t* ap;
        const bf16_t* wp;
        if (kh < 8) {
            ap = p.ctxb + arow * 2048 + kh * 256 + koff;
            wp = p.fp1 + ((size_t)nb * 80 + kh * 8) * 2048 + l * 8;
        } else {
            ap = h1r + arow * 512 + (kh - 8) * 256 + koff;
            wp = p.fp1 + ((size_t)nb * 80 + 64 + (kh - 8) * 8) * 2048 + l * 8;
        }
        f32x4 acc[4] = {};
#pragma unroll
        for (int i = 0; i < 8; ++i) {
            bf16x8 a8 = *(const bf16x8*)&ap[i * 32];
            const bf16_t* wk = wp + (size_t)i * 2048;
#pragma unroll
            for (int s = 0; s < 4; ++s) {
                bf16x8 w8 = *(const bf16x8*)&wk[s * 512];
                acc[s] = __builtin_amdgcn_mfma_f32_16x16x32_bf16(a8, w8, acc[s], 0, 0, 0);
            }
        }
        const int rb = w * 16 + ((l >> 4) << 2);
        const int d = nb * 16 + (l & 15);
        float* gp = p.G1p + (size_t)kh * (64 * 2048);
#pragma unroll
        for (int s = 0; s < 4; ++s)
#pragma unroll
            for (int j = 0; j < 4; ++j)
                gp[(rb + j) * 2048 + s * 512 + d] = acc[s][j];
    }
    bar_arrive(cB);

    if (bid < 128) {
        // ---------------- C: pw1 ----------------
        bar_wait(cB, 320);
        const int idx = bid * 256 + tid;
        const int row = idx >> 9, d = idx & 511;
        const bf16_t* xeb = p.xembb + (size_t)t * B_ * G4;
        float g[4];
#pragma unroll
        for (int s = 0; s < 4; ++s) g[s] = (float)xeb[row * 2048 + s * 512 + d];
#pragma unroll
        for (int kh = 0; kh < KH1; ++kh) {
            const float* gp = p.G1p + (size_t)kh * (64 * 2048) + row * 2048 + d;
#pragma unroll
            for (int s = 0; s < 4; ++s) g[s] += gp[s * 512];
        }
        float cn = sigf(g[1]) * c1r[idx] + sigf(g[0]) * tanhf(g[2]);
        c1w[idx] = cn;
        h1w[idx] = (bf16_t)(sigf(g[3]) * tanhf(cn));
        bar_arrive(cC);
    } else if (bid < 160) {
        // ---------------- D: gates2 full-K + pw2 (r8-verified P3 body) ----------------
        bar_wait(cC, 128);
        const int nb = bid - 128;
        const int arow = w * 16 + (l & 15);
        const int koff = (l >> 4) * 8;
        f32x4 acc[4] = {};
        const bf16_t* wp = p.fp2 + (size_t)nb * 32 * 2048 + l * 8;
        {   // h1 part: kf 0..15
            const bf16_t* ap = h1w + arow * 512 + koff;
            for (int kf = 0; kf < 16; ++kf) {
                bf16x8 a8 = *(const bf16x8*)&ap[kf * 32];
                const bf16_t* wk = wp + (size_t)kf * 2048;
#pragma unroll
                for (int s = 0; s < 4; ++s) {
                    bf16x8 w8 = *(const bf16x8*)&wk[s * 512];
                    acc[s] = __builtin_amdgcn_mfma_f32_16x16x32_bf16(a8, w8, acc[s], 0, 0, 0);
                }
            }
        }
        {   // h2 part: kf 16..31
            const bf16_t* ap = h2r + arow * 512 + koff;
            for (int kf = 0; kf < 16; ++kf) {
                bf16x8 a8 = *(const bf16x8*)&ap[kf * 32];
                const bf16_t* wk = wp + (size_t)(16 + kf) * 2048;
#pragma unroll
                for (int s = 0; s < 4; ++s) {
                    bf16x8 w8 = *(const bf16x8*)&wk[s * 512];
                    acc[s] = __builtin_amdgcn_mfma_f32_16x16x32_bf16(a8, w8, acc[s], 0, 0, 0);
                }
            }
        }
        const int rb = w * 16 + ((l >> 4) << 2);
        const int d = nb * 16 + (l & 15);
#pragma unroll
        for (int j = 0; j < 4; ++j) {
            int row = rb + j;
            float gi = acc[0][j] + p.bsum2[d];
            float gf = acc[1][j] + p.bsum2[512 + d];
            float gg = acc[2][j] + p.bsum2[1024 + d];
            float go = acc[3][j] + p.bsum2[1536 + d];
            float cn = sigf(gf) * c2r[row * 512 + d] + sigf(gi) * tanhf(gg);
            c2w[row * 512 + d] = cn;
            h2w[row * 512 + d] = (bf16_t)(sigf(go) * tanhf(cn));
        }
        bar_arrive(cD);

        // ---------------- E: hw(t+1) (r8-verified P0 body) ----------------
        bar_wait(cD, 32);
        {
            const int nt = nb;
            const bf16_t* ap = h2w + (w * 16 + (l & 15)) * 512 + (l >> 4) * 8;
            const bf16_t* wq = p.W2p + (size_t)nt * 16 * 512 + l * 8;
            f32x4 acc2 = {};
#pragma unroll
            for (int kf = 0; kf < 16; ++kf) {
                bf16x8 a8 = *(const bf16x8*)&ap[kf * 32];
                bf16x8 w8 = *(const bf16x8*)&wq[(size_t)kf * 512];
                acc2 = __builtin_amdgcn_mfma_f32_16x16x32_bf16(a8, w8, acc2, 0, 0, 0);
            }
            const int row = w * 16 + (l >> 4) * 4;
            const int col = nt * 16 + (l & 15);
#pragma unroll
            for (int j = 0; j < 4; ++j)
                p.hwb[(row + j) * 512 + col] = acc2[j] + p.b2[col];
        }
    }
    // blocks 160..319 exit after arriving at cB
}

// ---------------------------------------------------------------------------
extern "C" void kernel_launch(void* const* d_in, const int* in_sizes, int n_in,
                              void* d_out, int out_size, void* d_ws, size_t ws_size,
                              hipStream_t stream)
{
    const float* features = (const float*)d_in[0];
    const int*   captions = (const int*)d_in[1];
    const float* emb   = (const float*)d_in[2];
    const float* W1    = (const float*)d_in[3];
    const float* b1    = (const float*)d_in[4];
    const float* W2    = (const float*)d_in[5];
    const float* b2    = (const float*)d_in[6];
    const float* V     = (const float*)d_in[7];
    const float* bV    = (const float*)d_in[8];
    const float* W_ih1 = (const float*)d_in[9];
    const float* W_hh1 = (const float*)d_in[10];
    const float* b_ih1 = (const float*)d_in[11];
    const float* b_hh1 = (const float*)d_in[12];
    const float* W_ih2 = (const float*)d_in[13];
    const float* W_hh2 = (const float*)d_in[14];
    const float* b_ih2 = (const float*)d_in[15];
    const float* b_hh2 = (const float*)d_in[16];
    const float* fc_W  = (const float*)d_in[17];
    const float* fc_b  = (const float*)d_in[18];
    float* out = (float*)d_out;

    char* ws = (char*)d_ws;
    size_t off = 0;
    auto alloc = [&](size_t nbytes) {
        char* pp = ws + off;
        off = (off + nbytes + 255) & ~(size_t)255;
        return pp;
    };
    bf16_t* featb  = (bf16_t*)alloc(3136L * 2048 * 2);
    bf16_t* fW1b   = (bf16_t*)alloc(3136L * 512 * 2);
    bf16_t* W1b    = (bf16_t*)alloc(512L * 2048 * 2);
    bf16_t* W2p    = (bf16_t*)alloc(512L * 512 * 2);
    bf16_t* Wihel  = (bf16_t*)alloc(2048L * 256 * 2);
    bf16_t* fp1    = (bf16_t*)alloc(2048L * 2560 * 2);
    bf16_t* fp2    = (bf16_t*)alloc(2048L * 1024 * 2);
    bf16_t* fcWb   = (bf16_t*)alloc((size_t)VPAD * 512 * 2);
    bf16_t* xgb    = (bf16_t*)alloc(1920L * 256 * 2);
    bf16_t* xembb  = (bf16_t*)alloc(1920L * 2048 * 2);
    float*  bsum1  = (float*)alloc(2048 * 4);
    float*  bsum2  = (float*)alloc(2048 * 4);
    bf16_t* ctxb   = (bf16_t*)alloc((size_t)B_ * ENC * 2);
    float*  hwb    = (float*)alloc((size_t)B_ * ATT * 4);
    float*  G1p    = (float*)alloc((size_t)KH1 * B_ * G4 * 4);
    bf16_t* h1s    = (bf16_t*)alloc((size_t)(T_ + 1) * SL * 2);
    bf16_t* h2s    = (bf16_t*)alloc((size_t)(T_ + 1) * SL * 2);
    float*  c1s    = (float*)alloc(2L * SL * 4);
    float*  c2s    = (float*)alloc(2L * SL * 4);
    int*    cnt    = (int*)alloc((size_t)T_ * 4 * sizeof(int));

    prep_k<<<4096, 256, 0, stream>>>(
        b_ih1, b_hh1, bsum1, b_ih2, b_hh2, bsum2,
        W2, W2p, W1, W1b, W_ih1, Wihel, fp1,
        W_ih2, W_hh1, W_hh2, fp2, fc_W, fcWb,
        features, featb, captions, emb, xgb,
        b2, hwb, h1s, h2s, c1s, c2s, cnt);

    // fW1b = features @ W1^T + b1  (bf16 out)
    mm_bf16<0><<<dim3(ATT / 64, (B_ * P_) / 64), 256, 0, stream>>>(
        featb, ENC, W1b, ENC, b1, nullptr, fW1b, ATT, ATT, ENC);
    // xembb = xg @ Wih1[:, :256]^T + (b_ih1+b_hh1)  (bf16 out)
    mm_bf16<0><<<dim3(G4 / 64, (T_ * B_) / 64), 256, 0, stream>>>(
        xgb, EMBED, Wihel, EMBED, bsum1, nullptr, xembb, G4, G4, EMBED);

    SP sp { featb, fW1b, W2p, fp1, fp2, xembb,
            V, bV, b2, bsum2,
            ctxb, h1s, h2s, hwb, G1p, c1s, c2s, cnt };
    for (int t = 0; t < T_; ++t)
        step_k<<<320, 256, 0, stream>>>(sp, t);

    // out = h2(1..30) @ fc_W^T + fc_b  (f32 out, row remap t*64+b -> b*T+t)
    mm_bf16<2><<<dim3(VPAD / 64, (T_ * B_) / 64), 256, 0, stream>>>(
        h2s + SL, DEC, fcWb, DEC, fc_b, out, nullptr, VOCAB, VOCAB, DEC);
}

// Round 10
// 3879.729 us; speedup vs baseline: 1.2613x; 1.2613x over previous
//
#include <hip/hip_runtime.h>
#include <math.h>

#define VOCAB 10000
#define VPAD  10240   // padded so fc n-tile -> XCD map is stable (bid%8)
#define EMBED 256
#define ENC   2048
#define DEC   512
#define ATT   512
#define B_    64
#define P_    49
#define T_    30
#define G4    2048   // 4*DEC
#define SL    32768  // one state slice = B_*DEC

typedef __bf16 bf16_t;
typedef bf16_t bf16x8 __attribute__((ext_vector_type(8)));
typedef bf16_t bf16x2 __attribute__((ext_vector_type(2)));
typedef float  f32x4  __attribute__((ext_vector_type(4)));

__device__ __forceinline__ float sigf(float x) { return 1.f / (1.f + expf(-x)); }

// ---------------------------------------------------------------------------
// Inter-block barrier. r9 post-mortem: RMW-based polling (atomicAdd(cnt,0))
// from 320 blocks serialized the L2 atomic unit (~35us/barrier). Arrival stays
// an RMW; WAITERS use read-only atomic loads (AGENT scope, no ownership ->
// no serialization). Explicit __threadfence on both sides preserves the
// r9-hardware-proven data-visibility ordering. Counters zeroed by prep_k
// every call (graph-replay safe).
// ---------------------------------------------------------------------------
__device__ __forceinline__ void bar_arrive(int* cnt)
{
    __syncthreads();
    __threadfence();
    if (threadIdx.x == 0)
        __hip_atomic_fetch_add(cnt, 1, __ATOMIC_RELAXED, __HIP_MEMORY_SCOPE_AGENT);
}
__device__ __forceinline__ void bar_wait(int* cnt, int target)
{
    if (threadIdx.x == 0) {
        while (__hip_atomic_load(cnt, __ATOMIC_RELAXED, __HIP_MEMORY_SCOPE_AGENT) < target)
            __builtin_amdgcn_s_sleep(2);
    }
    __syncthreads();
    __threadfence();
}

// ---------------------------------------------------------------------------
// One-time prep: state/counter zeroing, hwb(t=0)=b2 rows, bias sums, bf16
// conversions, MFMA fragment packings (verified r5-r9):
// fp1h[((nb*16+kf)*4+s)*512+l*8+j] = W_hh1[s*512+nb*16+(l&15)][kf*32+(l>>4)*8+j]
// fp2 same with 32 kf (kf<16: Wih2, kf>=16: Whh2). W2p: 16-col strips of W2.
// ---------------------------------------------------------------------------
__global__ void prep_k(
    const float* __restrict__ b_ih1, const float* __restrict__ b_hh1, float* __restrict__ bsum1,
    const float* __restrict__ b_ih2, const float* __restrict__ b_hh2, float* __restrict__ bsum2,
    const float* __restrict__ W2,    bf16_t* __restrict__ W2p,
    const float* __restrict__ W_hh1, bf16_t* __restrict__ fp1h,
    const float* __restrict__ W_ih2, const float* __restrict__ W_hh2, bf16_t* __restrict__ fp2,
    const float* __restrict__ fc_W,  bf16_t* __restrict__ fcWb,
    const float* __restrict__ features, bf16_t* __restrict__ featb,
    const int* __restrict__ caps, const float* __restrict__ emb, bf16_t* __restrict__ xgb,
    const float* __restrict__ b2, float* __restrict__ hwb,
    bf16_t* __restrict__ h1s0, bf16_t* __restrict__ h2s0,
    float* __restrict__ c1s0, float* __restrict__ c2s0, int* __restrict__ cnt)
{
    long stride = (long)gridDim.x * blockDim.x;
    long i0 = (long)blockIdx.x * blockDim.x + threadIdx.x;
    for (long i = i0; i < T_ * 8; i += stride) cnt[i] = 0;
    for (long i = i0; i < SL; i += stride) {
        h1s0[i] = (bf16_t)0.f; h2s0[i] = (bf16_t)0.f;
        c1s0[i] = 0.f; c2s0[i] = 0.f;
        hwb[i] = b2[i & 511];          // hw(t=0) = 0 @ W2^T + b2
    }
    for (long i = i0; i < 2048; i += stride) {
        bsum1[i] = b_ih1[i] + b_hh1[i];
        bsum2[i] = b_ih2[i] + b_hh2[i];
    }
    for (long i = i0; i < 512L * 512; i += stride) {   // W2p fragment pack
        long j8 = i & 7, lq = (i >> 3) & 63, kf = (i >> 9) & 15, nt = i >> 13;
        W2p[i] = (bf16_t)W2[(nt * 16 + (lq & 15)) * 512 + kf * 32 + (lq >> 4) * 8 + j8];
    }
    for (long i = i0; i < 32L * 16 * 2048; i += stride) { // fp1h (Whh1 part)
        long j8 = i & 7, lq = (i >> 3) & 63, s = (i >> 9) & 3, nk = i >> 11;
        long kf = nk & 15, nb = nk >> 4;
        long c = s * 512 + nb * 16 + (lq & 15);
        long k = kf * 32 + (lq >> 4) * 8 + j8;
        fp1h[i] = (bf16_t)W_hh1[c * 512 + k];
    }
    for (long i = i0; i < 2048L * 1024; i += stride) { // fp2
        long j8 = i & 7, lq = (i >> 3) & 63, s = (i >> 9) & 3, nk = i >> 11;
        long kf = nk & 31, nb = nk >> 5;
        long c = s * 512 + nb * 16 + (lq & 15);
        long k = kf * 32 + (lq >> 4) * 8 + j8;
        fp2[i] = (bf16_t)(k < 512 ? W_ih2[c * 512 + k] : W_hh2[c * 512 + (k - 512)]);
    }
    for (long i = i0; i < (long)VPAD * 512; i += stride) {
        long r = i >> 9;
        fcWb[i] = (bf16_t)(r < VOCAB ? fc_W[i] : 0.f);
    }
    for (long i = i0; i < 3136L * 2048; i += stride) featb[i] = (bf16_t)features[i];
    for (long i = i0; i < 1920L * 256; i += stride) {
        long row = i >> 8, e = i & 255;
        long tq = row >> 6, b = row & 63;
        int cap = caps[b * T_ + tq];
        xgb[i] = (bf16_t)emb[(long)cap * 256 + e];
    }
}

// ---------------------------------------------------------------------------
// mm_f32b: C[M,N](bf16) = A(bf16)[M,K] @ B(f32,strided)[N,K]^T (+bias).
// B element (n,k) = Bw[n*ldb + boff + k] — reads f32 weights directly,
// converting during LDS staging (drops three packed-weight buffers).
// Same verified MFMA core as mm_bf16 (r2-r9).
// ---------------------------------------------------------------------------
__global__ __launch_bounds__(256) void mm_f32b(
    const bf16_t* __restrict__ A, int lda,
    const float* __restrict__ Bw, int ldb, int boff,
    const float* __restrict__ bias,
    bf16_t* __restrict__ outB, int ldo, int K)
{
    __shared__ bf16_t Apad[64][72];
    __shared__ bf16_t Bpad[64][72];
    const int bn = blockIdx.x * 64, bm = blockIdx.y * 64;
    const int tid = threadIdx.x;
    const int w = tid >> 6, l = tid & 63;
    f32x4 acc[4] = {};

    for (int k0 = 0; k0 < K; k0 += 64) {
        for (int c = tid; c < 512; c += 256) {
            int row = c >> 3, q = c & 7;
            *(bf16x8*)&Apad[row][q * 8] = *(const bf16x8*)&A[(size_t)(bm + row) * lda + k0 + q * 8];
            const float* bs = &Bw[(size_t)(bn + row) * ldb + boff + k0 + q * 8];
            float4 f0 = *(const float4*)bs;
            float4 f1 = *(const float4*)(bs + 4);
            bf16x8 v;
            v[0] = (bf16_t)f0.x; v[1] = (bf16_t)f0.y; v[2] = (bf16_t)f0.z; v[3] = (bf16_t)f0.w;
            v[4] = (bf16_t)f1.x; v[5] = (bf16_t)f1.y; v[6] = (bf16_t)f1.z; v[7] = (bf16_t)f1.w;
            *(bf16x8*)&Bpad[row][q * 8] = v;
        }
        __syncthreads();
#pragma unroll
        for (int ks = 0; ks < 2; ++ks) {
            bf16x8 a8 = *(const bf16x8*)&Apad[w * 16 + (l & 15)][ks * 32 + (l >> 4) * 8];
#pragma unroll
            for (int nf = 0; nf < 4; ++nf) {
                bf16x8 b8 = *(const bf16x8*)&Bpad[nf * 16 + (l & 15)][ks * 32 + (l >> 4) * 8];
                acc[nf] = __builtin_amdgcn_mfma_f32_16x16x32_bf16(a8, b8, acc[nf], 0, 0, 0);
            }
        }
        __syncthreads();
    }

    int rbase = bm + w * 16 + (l >> 4) * 4;
    int cl = l & 15;
#pragma unroll
    for (int nf = 0; nf < 4; ++nf) {
        int col = bn + nf * 16 + cl;
        float bv = bias ? bias[col] : 0.f;
#pragma unroll
        for (int j = 0; j < 4; ++j)
            outB[(size_t)(rbase + j) * ldo + col] = (bf16_t)(acc[nf][j] + bv);
    }
}

// ---------------------------------------------------------------------------
// fc GEMM (bf16 A/B, f32 out, row remap + N guard) — verified r6-r9.
// ---------------------------------------------------------------------------
__global__ __launch_bounds__(256) void mm_fc(
    const bf16_t* __restrict__ A, int lda,
    const bf16_t* __restrict__ Bw, int ldb,
    const float* __restrict__ bias,
    float* __restrict__ outF, int ldo, int N, int K)
{
    __shared__ bf16_t Apad[64][72];
    __shared__ bf16_t Bpad[64][72];
    const int bn = blockIdx.x * 64, bm = blockIdx.y * 64;
    const int tid = threadIdx.x;
    const int w = tid >> 6, l = tid & 63;
    f32x4 acc[4] = {};

    for (int k0 = 0; k0 < K; k0 += 64) {
        for (int c = tid; c < 512; c += 256) {
            int row = c >> 3, q = c & 7;
            *(bf16x8*)&Apad[row][q * 8] = *(const bf16x8*)&A[(size_t)(bm + row) * lda + k0 + q * 8];
            *(bf16x8*)&Bpad[row][q * 8] = *(const bf16x8*)&Bw[(size_t)(bn + row) * ldb + k0 + q * 8];
        }
        __syncthreads();
#pragma unroll
        for (int ks = 0; ks < 2; ++ks) {
            bf16x8 a8 = *(const bf16x8*)&Apad[w * 16 + (l & 15)][ks * 32 + (l >> 4) * 8];
#pragma unroll
            for (int nf = 0; nf < 4; ++nf) {
                bf16x8 b8 = *(const bf16x8*)&Bpad[nf * 16 + (l & 15)][ks * 32 + (l >> 4) * 8];
                acc[nf] = __builtin_amdgcn_mfma_f32_16x16x32_bf16(a8, b8, acc[nf], 0, 0, 0);
            }
        }
        __syncthreads();
    }

    int rbase = bm + w * 16 + (l >> 4) * 4;
    int cl = l & 15;
#pragma unroll
    for (int nf = 0; nf < 4; ++nf) {
        int col = bn + nf * 16 + cl;
#pragma unroll
        for (int j = 0; j < 4; ++j) {
            int row = rbase + j;
            if (col < N) {
                int orow = (row & 63) * T_ + (row >> 6);  // t*64+b -> b*T+t
                outF[(size_t)orow * ldo + col] = acc[nf][j] + bias[col];
            }
        }
    }
}

// ===========================================================================
// ONE KERNEL PER STEP: 256 blocks x 256 threads, 5 load-poll barriers.
//  A1 (bid<64)    scores+softmax (reads hwb)            -> wn_g      [cA1=64]
//  B' (64..127)   gates1 h1-part partials (NO WAITS)    -> G1p[2]    [cBp=64]
//  A2 (all 256)   wait cA1; g1pre = sum_p wn*F1g        -> g1pre     [cA2=256]
//  C  (bid<128)   wait cA2,cBp; pw1: xe+g1pre+G1p,LSTM1 -> h1(t+1)   [cC=128]
//  D  (128..159)  wait cC; gates2 full-K + LSTM2        -> h2(t+1)   [cD=32]
//  E  (same 32)   wait cD; hw(t+1) = h2 @ W2^T + b2     -> hwb
// F1g trick: gates1_ctx = (sum_p w_p feat_p) @ Wc^T == sum_p w_p (feat_p@Wc^T)
// — exact reorder; F1g precomputed once, kills the 10.5MB/step fp1-ctx stream.
// ===========================================================================
struct SP {
    const bf16_t *featb, *fW1b, *F1g, *W2p, *fp1h, *fp2, *xembb;
    const float *V, *bV, *b2, *bsum2;
    bf16_t *h1s, *h2s;
    float *hwb, *wn_g, *g1pre, *G1p, *c1s, *c2s;
    int *cnt;
};

__global__ __launch_bounds__(256) void step_k(SP p, int t)
{
    const int bid = blockIdx.x;
    const int tid = threadIdx.x;
    const int w = tid >> 6, l = tid & 63;
    __shared__ float sc[64];
    __shared__ float wn[64];

    int* cA1 = p.cnt + t * 8 + 0;   // target 64
    int* cBp = p.cnt + t * 8 + 1;   // target 64
    int* cA2 = p.cnt + t * 8 + 2;   // target 256
    int* cC  = p.cnt + t * 8 + 3;   // target 128
    int* cD  = p.cnt + t * 8 + 4;   // target 32

    const bf16_t* h1r = p.h1s + (size_t)t * SL;
    bf16_t* h1w = p.h1s + (size_t)(t + 1) * SL;
    const bf16_t* h2r = p.h2s + (size_t)t * SL;
    bf16_t* h2w = p.h2s + (size_t)(t + 1) * SL;
    const float* c1r = p.c1s + (size_t)(t & 1) * SL;
    float* c1w = p.c1s + (size_t)((t + 1) & 1) * SL;
    const float* c2r = p.c2s + (size_t)(t & 1) * SL;
    float* c2w = p.c2s + (size_t)((t + 1) & 1) * SL;

    if (bid < 64) {
        // ---------------- A1: scores + softmax ----------------
        const int b = bid;
        {
            float hwr[8], Vr[8];
#pragma unroll
            for (int i = 0; i < 8; ++i) { hwr[i] = p.hwb[b * 512 + l * 8 + i]; Vr[i] = p.V[l * 8 + i]; }
            for (int pq = w; pq < P_; pq += 4) {
                bf16x8 f8 = *(const bf16x8*)&p.fW1b[(size_t)(b * P_ + pq) * 512 + l * 8];
                float s = 0.f;
#pragma unroll
                for (int i = 0; i < 8; ++i) s += tanhf((float)f8[i] + hwr[i]) * Vr[i];
#pragma unroll
                for (int o = 32; o; o >>= 1) s += __shfl_xor(s, o);
                if (l == 0) sc[pq] = s + p.bV[0];
            }
        }
        __syncthreads();
        {
            float m = -1e30f;
            for (int q = 0; q < P_; ++q) m = fmaxf(m, sc[q]);
            float ss = 0.f;
            for (int q = 0; q < P_; ++q) ss += expf(sc[q] - m);
            if (tid < P_) p.wn_g[b * P_ + tid] = expf(sc[tid] - m) / ss;
        }
        bar_arrive(cA1);
    } else if (bid < 128) {
        // ---------------- B': gates1 h1-part (no intra-step deps) ----------------
        const int nb = (bid - 64) & 31, kh = (bid - 64) >> 5;  // kh in {0,1}
        const int arow = w * 16 + (l & 15);
        const int koff = (l >> 4) * 8;
        const bf16_t* ap = h1r + arow * 512 + kh * 256 + koff;
        const bf16_t* wp = p.fp1h + ((size_t)nb * 16 + kh * 8) * 2048 + l * 8;
        f32x4 acc[4] = {};
#pragma unroll
        for (int i = 0; i < 8; ++i) {
            bf16x8 a8 = *(const bf16x8*)&ap[i * 32];
            const bf16_t* wk = wp + (size_t)i * 2048;
#pragma unroll
            for (int s = 0; s < 4; ++s) {
                bf16x8 w8 = *(const bf16x8*)&wk[s * 512];
                acc[s] = __builtin_amdgcn_mfma_f32_16x16x32_bf16(a8, w8, acc[s], 0, 0, 0);
            }
        }
        const int rb = w * 16 + ((l >> 4) << 2);
        const int d = nb * 16 + (l & 15);
        float* gp = p.G1p + (size_t)kh * (64 * 2048);
#pragma unroll
        for (int s = 0; s < 4; ++s)
#pragma unroll
            for (int j = 0; j < 4; ++j)
                gp[(rb + j) * 2048 + s * 512 + d] = acc[s][j];
        bar_arrive(cBp);
    }

    // ---------------- A2: g1pre[b][q-slice] = sum_p wn[p] * F1g[b][p][...] ----------------
    bar_wait(cA1, 64);
    {
        const int b = bid >> 2, q = bid & 3;
        if (tid < P_) wn[tid] = p.wn_g[b * P_ + tid];
        __syncthreads();
        const bf16_t* fg = p.F1g + (size_t)b * P_ * 2048 + q * 512 + tid * 2;
        float a0 = 0.f, a1 = 0.f;
        for (int pq = 0; pq < P_; ++pq) {
            bf16x2 v = *(const bf16x2*)&fg[(size_t)pq * 2048];
            float wq = wn[pq];
            a0 += wq * (float)v[0];
            a1 += wq * (float)v[1];
        }
        float2 o2 = { a0, a1 };
        *(float2*)&p.g1pre[b * 2048 + q * 512 + tid * 2] = o2;
    }
    bar_arrive(cA2);

    if (bid < 128) {
        // ---------------- C: pw1 (xembb + g1pre + G1p[0] + G1p[1], LSTM1) ----------------
        bar_wait(cA2, 256);
        bar_wait(cBp, 64);
        const int idx = bid * 256 + tid;
        const int row = idx >> 9, d = idx & 511;
        const bf16_t* xeb = p.xembb + (size_t)t * B_ * G4;
        float g[4];
#pragma unroll
        for (int s = 0; s < 4; ++s) {
            int o = row * 2048 + s * 512 + d;
            g[s] = (float)xeb[o] + p.g1pre[o] + p.G1p[o] + p.G1p[64 * 2048 + o];
        }
        float cn = sigf(g[1]) * c1r[idx] + sigf(g[0]) * tanhf(g[2]);
        c1w[idx] = cn;
        h1w[idx] = (bf16_t)(sigf(g[3]) * tanhf(cn));
        bar_arrive(cC);
    } else if (bid < 160) {
        // ---------------- D: gates2 full-K + LSTM2 (r8/r9-verified body) ----------------
        bar_wait(cC, 128);
        const int nb = bid - 128;
        const int arow = w * 16 + (l & 15);
        const int koff = (l >> 4) * 8;
        f32x4 acc[4] = {};
        const bf16_t* wp = p.fp2 + (size_t)nb * 32 * 2048 + l * 8;
        {   // h1 part: kf 0..15
            const bf16_t* ap = h1w + arow * 512 + koff;
            for (int kf = 0; kf < 16; ++kf) {
                bf16x8 a8 = *(const bf16x8*)&ap[kf * 32];
                const bf16_t* wk = wp + (size_t)kf * 2048;
#pragma unroll
                for (int s = 0; s < 4; ++s) {
                    bf16x8 w8 = *(const bf16x8*)&wk[s * 512];
                    acc[s] = __builtin_amdgcn_mfma_f32_16x16x32_bf16(a8, w8, acc[s], 0, 0, 0);
                }
            }
        }
        {   // h2 part: kf 16..31
            const bf16_t* ap = h2r + arow * 512 + koff;
            for (int kf = 0; kf < 16; ++kf) {
                bf16x8 a8 = *(const bf16x8*)&ap[kf * 32];
                const bf16_t* wk = wp + (size_t)(16 + kf) * 2048;
#pragma unroll
                for (int s = 0; s < 4; ++s) {
                    bf16x8 w8 = *(const bf16x8*)&wk[s * 512];
                    acc[s] = __builtin_amdgcn_mfma_f32_16x16x32_bf16(a8, w8, acc[s], 0, 0, 0);
                }
            }
        }
        const int rb = w * 16 + ((l >> 4) << 2);
        const int d = nb * 16 + (l & 15);
#pragma unroll
        for (int j = 0; j < 4; ++j) {
            int row = rb + j;
            float gi = acc[0][j] + p.bsum2[d];
            float gf = acc[1][j] + p.bsum2[512 + d];
            float gg = acc[2][j] + p.bsum2[1024 + d];
            float go = acc[3][j] + p.bsum2[1536 + d];
            float cn = sigf(gf) * c2r[row * 512 + d] + sigf(gi) * tanhf(gg);
            c2w[row * 512 + d] = cn;
            h2w[row * 512 + d] = (bf16_t)(sigf(go) * tanhf(cn));
        }
        bar_arrive(cD);

        // ---------------- E: hw(t+1) (r8/r9-verified body) ----------------
        bar_wait(cD, 32);
        {
            const int nt = nb;
            const bf16_t* ap = h2w + (w * 16 + (l & 15)) * 512 + (l >> 4) * 8;
            const bf16_t* wq = p.W2p + (size_t)nt * 16 * 512 + l * 8;
            f32x4 acc2 = {};
#pragma unroll
            for (int kf = 0; kf < 16; ++kf) {
                bf16x8 a8 = *(const bf16x8*)&ap[kf * 32];
                bf16x8 w8 = *(const bf16x8*)&wq[(size_t)kf * 512];
                acc2 = __builtin_amdgcn_mfma_f32_16x16x32_bf16(a8, w8, acc2, 0, 0, 0);
            }
            const int row = w * 16 + (l >> 4) * 4;
            const int col = nt * 16 + (l & 15);
#pragma unroll
            for (int j = 0; j < 4; ++j)
                p.hwb[(row + j) * 512 + col] = acc2[j] + p.b2[col];
        }
    }
    // bid 160..255 exit after A2
}

// ---------------------------------------------------------------------------
extern "C" void kernel_launch(void* const* d_in, const int* in_sizes, int n_in,
                              void* d_out, int out_size, void* d_ws, size_t ws_size,
                              hipStream_t stream)
{
    const float* features = (const float*)d_in[0];
    const int*   captions = (const int*)d_in[1];
    const float* emb   = (const float*)d_in[2];
    const float* W1    = (const float*)d_in[3];
    const float* b1    = (const float*)d_in[4];
    const float* W2    = (const float*)d_in[5];
    const float* b2    = (const float*)d_in[6];
    const float* V     = (const float*)d_in[7];
    const float* bV    = (const float*)d_in[8];
    const float* W_ih1 = (const float*)d_in[9];
    const float* W_hh1 = (const float*)d_in[10];
    const float* b_ih1 = (const float*)d_in[11];
    const float* b_hh1 = (const float*)d_in[12];
    const float* W_ih2 = (const float*)d_in[13];
    const float* W_hh2 = (const float*)d_in[14];
    const float* b_ih2 = (const float*)d_in[15];
    const float* b_hh2 = (const float*)d_in[16];
    const float* fc_W  = (const float*)d_in[17];
    const float* fc_b  = (const float*)d_in[18];
    float* out = (float*)d_out;

    char* ws = (char*)d_ws;
    size_t off = 0;
    auto alloc = [&](size_t nbytes) {
        char* pp = ws + off;
        off = (off + nbytes + 255) & ~(size_t)255;
        return pp;
    };
    bf16_t* featb  = (bf16_t*)alloc(3136L * 2048 * 2);   // 12.8 MB
    bf16_t* fW1b   = (bf16_t*)alloc(3136L * 512 * 2);    // 3.2 MB
    bf16_t* F1g    = (bf16_t*)alloc(3136L * 2048 * 2);   // 12.8 MB
    bf16_t* W2p    = (bf16_t*)alloc(512L * 512 * 2);
    bf16_t* fp1h   = (bf16_t*)alloc(32L * 16 * 2048 * 2); // 2.1 MB
    bf16_t* fp2    = (bf16_t*)alloc(2048L * 1024 * 2);   // 4.2 MB
    bf16_t* fcWb   = (bf16_t*)alloc((size_t)VPAD * 512 * 2);  // 10.5 MB
    bf16_t* xgb    = (bf16_t*)alloc(1920L * 256 * 2);
    bf16_t* xembb  = (bf16_t*)alloc(1920L * 2048 * 2);   // 7.9 MB
    float*  bsum1  = (float*)alloc(2048 * 4);
    float*  bsum2  = (float*)alloc(2048 * 4);
    float*  hwb    = (float*)alloc((size_t)B_ * ATT * 4);
    float*  wn_g   = (float*)alloc((size_t)B_ * P_ * 4);
    float*  g1pre  = (float*)alloc((size_t)B_ * G4 * 4);
    float*  G1p    = (float*)alloc(2L * B_ * G4 * 4);    // 1.0 MB
    bf16_t* h1s    = (bf16_t*)alloc((size_t)(T_ + 1) * SL * 2);
    bf16_t* h2s    = (bf16_t*)alloc((size_t)(T_ + 1) * SL * 2);
    float*  c1s    = (float*)alloc(2L * SL * 4);
    float*  c2s    = (float*)alloc(2L * SL * 4);
    int*    cnt    = (int*)alloc((size_t)T_ * 8 * sizeof(int));
    // total ~63 MB (< proven 68.5 MB)

    prep_k<<<4096, 256, 0, stream>>>(
        b_ih1, b_hh1, bsum1, b_ih2, b_hh2, bsum2,
        W2, W2p, W_hh1, fp1h, W_ih2, W_hh2, fp2, fc_W, fcWb,
        features, featb, captions, emb, xgb,
        b2, hwb, h1s, h2s, c1s, c2s, cnt);

    // fW1b = featb @ W1^T + b1           [3136 x 512], K=2048
    mm_f32b<<<dim3(ATT / 64, 3136 / 64), 256, 0, stream>>>(
        featb, ENC, W1, ENC, 0, b1, fW1b, ATT, ENC);
    // xembb = xgb @ Wih1[:, :256]^T + bsum1   [1920 x 2048], K=256
    mm_f32b<<<dim3(G4 / 64, (T_ * B_) / 64), 256, 0, stream>>>(
        xgb, EMBED, W_ih1, EMBED + ENC, 0, bsum1, xembb, G4, EMBED);
    // F1g = featb @ Wih1[:, 256:2304]^T   [3136 x 2048], K=2048 (no bias)
    mm_f32b<<<dim3(G4 / 64, 3136 / 64), 256, 0, stream>>>(
        featb, ENC, W_ih1, EMBED + ENC, EMBED, nullptr, F1g, G4, ENC);

    SP sp { featb, fW1b, F1g, W2p, fp1h, fp2, xembb,
            V, bV, b2, bsum2,
            h1s, h2s, hwb, wn_g, g1pre, G1p, c1s, c2s, cnt };
    for (int t = 0; t < T_; ++t)
        step_k<<<256, 256, 0, stream>>>(sp, t);

    // out = h2(1..30) @ fc_W^T + fc_b  (f32 out, row remap t*64+b -> b*T+t)
    mm_fc<<<dim3(VPAD / 64, (T_ * B_) / 64), 256, 0, stream>>>(
        h2s + SL, DEC, fcWb, DEC, fc_b, out, VOCAB, VOCAB, DEC);
}

// Round 11
// 2530.364 us; speedup vs baseline: 1.9338x; 1.5333x over previous
//
#include <hip/hip_runtime.h>
#include <math.h>

#define VOCAB 10000
#define VPAD  10240   // padded so fc n-tile -> XCD map is stable (bid%8)
#define EMBED 256
#define ENC   2048
#define DEC   512
#define ATT   512
#define B_    64
#define P_    49
#define T_    30
#define G4    2048   // 4*DEC
#define SL    32768  // one state slice = B_*DEC (= 64*512)

typedef __bf16 bf16_t;
typedef bf16_t bf16x8 __attribute__((ext_vector_type(8)));
typedef bf16_t bf16x2 __attribute__((ext_vector_type(2)));
typedef float  f32x4  __attribute__((ext_vector_type(4)));

__device__ __forceinline__ float sigf(float x) { return 1.f / (1.f + expf(-x)); }

// ---------------------------------------------------------------------------
// One-time prep. NO barriers/atomics anywhere anymore — all cross-block sync
// is kernel boundaries (measured ~9us vs 25-70us for in-kernel barriers on
// this chip; agent-scope fences force cross-XCD L2 writeback — r8/r10 PM).
// Packings (verified r5-r10):
//  fp1h[((nb*16+kf)*4+s)*512+l*8+j] = W_hh1[s*512+nb*16+(l&15)][kf*32+(l>>4)*8+j]
//  fp2 same with 32 kf (kf<16: Wih2, kf>=16: Whh2).
//  W2sp[((nb*32+nt)*64+lq)*8+j]: B-frag of W2 col-strip nb, K=32 zero-padded
//    (k=(lq>>4)*8+j; k<16 -> W2[(nt*16+(lq&15))*512 + nb*16 + k], else 0).
// Zeroed per call: h1s/h2s slice0, c slices, hwp (K1(0) then yields hw=b2),
// G1h (h1(0)=0).
// ---------------------------------------------------------------------------
__global__ void prep_k(
    const float* __restrict__ b_ih1, const float* __restrict__ b_hh1, float* __restrict__ bsum1,
    const float* __restrict__ b_ih2, const float* __restrict__ b_hh2, float* __restrict__ bsum2,
    const float* __restrict__ W2,    bf16_t* __restrict__ W2sp,
    const float* __restrict__ W_hh1, bf16_t* __restrict__ fp1h,
    const float* __restrict__ W_ih2, const float* __restrict__ W_hh2, bf16_t* __restrict__ fp2,
    const float* __restrict__ fc_W,  bf16_t* __restrict__ fcWb,
    const float* __restrict__ features, bf16_t* __restrict__ featb,
    const int* __restrict__ caps, const float* __restrict__ emb, bf16_t* __restrict__ xgb,
    bf16_t* __restrict__ h1s0, bf16_t* __restrict__ h2s0,
    float* __restrict__ c1s0, float* __restrict__ c2s0,
    float* __restrict__ hwp, float* __restrict__ G1h)
{
    long stride = (long)gridDim.x * blockDim.x;
    long i0 = (long)blockIdx.x * blockDim.x + threadIdx.x;
    for (long i = i0; i < SL; i += stride) {
        h1s0[i] = (bf16_t)0.f; h2s0[i] = (bf16_t)0.f;
        c1s0[i] = 0.f; c2s0[i] = 0.f;
    }
    for (long i = i0; i < 32L * SL; i += stride) hwp[i] = 0.f;
    for (long i = i0; i < 64L * 2048; i += stride) G1h[i] = 0.f;
    for (long i = i0; i < 2048; i += stride) {
        bsum1[i] = b_ih1[i] + b_hh1[i];
        bsum2[i] = b_ih2[i] + b_hh2[i];
    }
    for (long i = i0; i < 32L * 32 * 64 * 8; i += stride) {  // W2sp (1 MB)
        long j8 = i & 7, lq = (i >> 3) & 63, nt = (i >> 9) & 31, nb = i >> 14;
        long k = (lq >> 4) * 8 + j8;
        long a = nt * 16 + (lq & 15);
        W2sp[i] = (bf16_t)(k < 16 ? W2[a * 512 + nb * 16 + k] : 0.f);
    }
    for (long i = i0; i < 32L * 16 * 2048; i += stride) { // fp1h (Whh1 part)
        long j8 = i & 7, lq = (i >> 3) & 63, s = (i >> 9) & 3, nk = i >> 11;
        long kf = nk & 15, nb = nk >> 4;
        long c = s * 512 + nb * 16 + (lq & 15);
        long k = kf * 32 + (lq >> 4) * 8 + j8;
        fp1h[i] = (bf16_t)W_hh1[c * 512 + k];
    }
    for (long i = i0; i < 2048L * 1024; i += stride) { // fp2
        long j8 = i & 7, lq = (i >> 3) & 63, s = (i >> 9) & 3, nk = i >> 11;
        long kf = nk & 31, nb = nk >> 5;
        long c = s * 512 + nb * 16 + (lq & 15);
        long k = kf * 32 + (lq >> 4) * 8 + j8;
        fp2[i] = (bf16_t)(k < 512 ? W_ih2[c * 512 + k] : W_hh2[c * 512 + (k - 512)]);
    }
    for (long i = i0; i < (long)VPAD * 512; i += stride) {
        long r = i >> 9;
        fcWb[i] = (bf16_t)(r < VOCAB ? fc_W[i] : 0.f);
    }
    for (long i = i0; i < 3136L * 2048; i += stride) featb[i] = (bf16_t)features[i];
    for (long i = i0; i < 1920L * 256; i += stride) {
        long row = i >> 8, e = i & 255;
        long tq = row >> 6, b = row & 63;
        int cap = caps[b * T_ + tq];
        xgb[i] = (bf16_t)emb[(long)cap * 256 + e];
    }
}

// ---------------------------------------------------------------------------
// mm_f32b: C[M,N](bf16) = A(bf16)[M,K] @ B(f32,strided)[N,K]^T (+bias).
// Verified r10 (converts f32 weights during LDS staging).
// ---------------------------------------------------------------------------
__global__ __launch_bounds__(256) void mm_f32b(
    const bf16_t* __restrict__ A, int lda,
    const float* __restrict__ Bw, int ldb, int boff,
    const float* __restrict__ bias,
    bf16_t* __restrict__ outB, int ldo, int K)
{
    __shared__ bf16_t Apad[64][72];
    __shared__ bf16_t Bpad[64][72];
    const int bn = blockIdx.x * 64, bm = blockIdx.y * 64;
    const int tid = threadIdx.x;
    const int w = tid >> 6, l = tid & 63;
    f32x4 acc[4] = {};

    for (int k0 = 0; k0 < K; k0 += 64) {
        for (int c = tid; c < 512; c += 256) {
            int row = c >> 3, q = c & 7;
            *(bf16x8*)&Apad[row][q * 8] = *(const bf16x8*)&A[(size_t)(bm + row) * lda + k0 + q * 8];
            const float* bs = &Bw[(size_t)(bn + row) * ldb + boff + k0 + q * 8];
            float4 f0 = *(const float4*)bs;
            float4 f1 = *(const float4*)(bs + 4);
            bf16x8 v;
            v[0] = (bf16_t)f0.x; v[1] = (bf16_t)f0.y; v[2] = (bf16_t)f0.z; v[3] = (bf16_t)f0.w;
            v[4] = (bf16_t)f1.x; v[5] = (bf16_t)f1.y; v[6] = (bf16_t)f1.z; v[7] = (bf16_t)f1.w;
            *(bf16x8*)&Bpad[row][q * 8] = v;
        }
        __syncthreads();
#pragma unroll
        for (int ks = 0; ks < 2; ++ks) {
            bf16x8 a8 = *(const bf16x8*)&Apad[w * 16 + (l & 15)][ks * 32 + (l >> 4) * 8];
#pragma unroll
            for (int nf = 0; nf < 4; ++nf) {
                bf16x8 b8 = *(const bf16x8*)&Bpad[nf * 16 + (l & 15)][ks * 32 + (l >> 4) * 8];
                acc[nf] = __builtin_amdgcn_mfma_f32_16x16x32_bf16(a8, b8, acc[nf], 0, 0, 0);
            }
        }
        __syncthreads();
    }

    int rbase = bm + w * 16 + (l >> 4) * 4;
    int cl = l & 15;
#pragma unroll
    for (int nf = 0; nf < 4; ++nf) {
        int col = bn + nf * 16 + cl;
        float bv = bias ? bias[col] : 0.f;
#pragma unroll
        for (int j = 0; j < 4; ++j)
            outB[(size_t)(rbase + j) * ldo + col] = (bf16_t)(acc[nf][j] + bv);
    }
}

// ---------------------------------------------------------------------------
// fc GEMM (bf16 A/B, f32 out, row remap + N guard) — verified r6-r10.
// ---------------------------------------------------------------------------
__global__ __launch_bounds__(256) void mm_fc(
    const bf16_t* __restrict__ A, int lda,
    const bf16_t* __restrict__ Bw, int ldb,
    const float* __restrict__ bias,
    float* __restrict__ outF, int ldo, int N, int K)
{
    __shared__ bf16_t Apad[64][72];
    __shared__ bf16_t Bpad[64][72];
    const int bn = blockIdx.x * 64, bm = blockIdx.y * 64;
    const int tid = threadIdx.x;
    const int w = tid >> 6, l = tid & 63;
    f32x4 acc[4] = {};

    for (int k0 = 0; k0 < K; k0 += 64) {
        for (int c = tid; c < 512; c += 256) {
            int row = c >> 3, q = c & 7;
            *(bf16x8*)&Apad[row][q * 8] = *(const bf16x8*)&A[(size_t)(bm + row) * lda + k0 + q * 8];
            *(bf16x8*)&Bpad[row][q * 8] = *(const bf16x8*)&Bw[(size_t)(bn + row) * ldb + k0 + q * 8];
        }
        __syncthreads();
#pragma unroll
        for (int ks = 0; ks < 2; ++ks) {
            bf16x8 a8 = *(const bf16x8*)&Apad[w * 16 + (l & 15)][ks * 32 + (l >> 4) * 8];
#pragma unroll
            for (int nf = 0; nf < 4; ++nf) {
                bf16x8 b8 = *(const bf16x8*)&Bpad[nf * 16 + (l & 15)][ks * 32 + (l >> 4) * 8];
                acc[nf] = __builtin_amdgcn_mfma_f32_16x16x32_bf16(a8, b8, acc[nf], 0, 0, 0);
            }
        }
        __syncthreads();
    }

    int rbase = bm + w * 16 + (l >> 4) * 4;
    int cl = l & 15;
#pragma unroll
    for (int nf = 0; nf < 4; ++nf) {
        int col = bn + nf * 16 + cl;
#pragma unroll
        for (int j = 0; j < 4; ++j) {
            int row = rbase + j;
            if (col < N) {
                int orow = (row & 63) * T_ + (row >> 6);  // t*64+b -> b*T+t
                outF[(size_t)orow * ldo + col] = acc[nf][j] + bias[col];
            }
        }
    }
}

// ===========================================================================
// STEP KERNEL 1 — fully per-batch (64 blocks x 256 thr, no cross-block deps):
//  hw[b] = b2 + sum_nb hwp[nb][b][:]  (partials from gate2_k of step t-1)
//  scores + softmax (r7-verified body, hw from LDS)
//  g1pre = sum_p wn[p] * F1g[b][p][:]  (F1g trick, exact reorder — r10-proven)
//  pw1:  gates1 = xembb + g1pre + G1h[b]  -> LSTM1 -> h1(t+1)[b], c1
// ===========================================================================
__global__ __launch_bounds__(256) void attn1_k(
    const float* __restrict__ hwp, const float* __restrict__ b2,
    const bf16_t* __restrict__ fW1b, const float* __restrict__ V,
    const float* __restrict__ bV, const bf16_t* __restrict__ F1g,
    const bf16_t* __restrict__ xeb, const float* __restrict__ G1h,
    const float* __restrict__ c1r, float* __restrict__ c1w,
    bf16_t* __restrict__ h1w)
{
    const int b = blockIdx.x, tid = threadIdx.x;
    const int w = tid >> 6, l = tid & 63;
    __shared__ float hw[512];
    __shared__ float sc[64];
    __shared__ float wn[64];
    __shared__ float gsum[2048];

    {   // hw reduce over 32 partials
        float a0 = b2[2 * tid], a1 = b2[2 * tid + 1];
        const float* hp = hwp + b * 512 + 2 * tid;
#pragma unroll 8
        for (int nb = 0; nb < 32; ++nb) {
            float2 v = *(const float2*)&hp[(size_t)nb * SL];
            a0 += v.x; a1 += v.y;
        }
        hw[2 * tid] = a0; hw[2 * tid + 1] = a1;
    }
    __syncthreads();
    {   // scores
        float hwr[8], Vr[8];
#pragma unroll
        for (int i = 0; i < 8; ++i) { hwr[i] = hw[l * 8 + i]; Vr[i] = V[l * 8 + i]; }
        for (int pq = w; pq < P_; pq += 4) {
            bf16x8 f8 = *(const bf16x8*)&fW1b[(size_t)(b * P_ + pq) * 512 + l * 8];
            float s = 0.f;
#pragma unroll
            for (int i = 0; i < 8; ++i) s += tanhf((float)f8[i] + hwr[i]) * Vr[i];
#pragma unroll
            for (int o = 32; o; o >>= 1) s += __shfl_xor(s, o);
            if (l == 0) sc[pq] = s + bV[0];
        }
    }
    __syncthreads();
    {   // softmax
        float m = -1e30f;
        for (int q = 0; q < P_; ++q) m = fmaxf(m, sc[q]);
        float ss = 0.f;
        for (int q = 0; q < P_; ++q) ss += expf(sc[q] - m);
        if (tid < P_) wn[tid] = expf(sc[tid] - m) / ss;
    }
    __syncthreads();
    {   // g1pre -> gsum (LDS)
        for (int s = 0; s < 4; ++s) {
            const bf16_t* fg = F1g + (size_t)b * P_ * 2048 + s * 512 + tid * 2;
            float a0 = 0.f, a1 = 0.f;
            for (int q = 0; q < P_; ++q) {
                bf16x2 v = *(const bf16x2*)&fg[(size_t)q * 2048];
                float wq = wn[q];
                a0 += wq * (float)v[0];
                a1 += wq * (float)v[1];
            }
            gsum[s * 512 + 2 * tid] = a0;
            gsum[s * 512 + 2 * tid + 1] = a1;
        }
    }
    __syncthreads();
    {   // pw1 (batch-row-local)
        const bf16_t* xb = xeb + (size_t)b * G4;
        const float* gh = G1h + b * 2048;
#pragma unroll
        for (int u = 0; u < 2; ++u) {
            int d = 2 * tid + u;
            float gi = (float)xb[d]        + gsum[d]        + gh[d];
            float gf = (float)xb[512 + d]  + gsum[512 + d]  + gh[512 + d];
            float gg = (float)xb[1024 + d] + gsum[1024 + d] + gh[1024 + d];
            float go = (float)xb[1536 + d] + gsum[1536 + d] + gh[1536 + d];
            int idx = b * 512 + d;
            float cn = sigf(gf) * c1r[idx] + sigf(gi) * tanhf(gg);
            c1w[idx] = cn;
            h1w[idx] = (bf16_t)(sigf(go) * tanhf(cn));
        }
    }
}

// ===========================================================================
// STEP KERNEL 2 — per-d-strip (32 blocks x 256 thr, no cross-block deps):
//  G1h(t+1)[:, strip] = h1(t+1) @ Whh1^T        (r10 B' body, both halves)
//  gates2 full-K + pw2 -> h2(t+1)[:, strip]     (r8-r10 D body)
//  hwp[nb] = h2strip (K=16, zero-pad 32) @ W2sp (next step's hw partial)
// ===========================================================================
__global__ __launch_bounds__(256) void gate2_k(
    const bf16_t* __restrict__ h1n, const bf16_t* __restrict__ h2r,
    const bf16_t* __restrict__ fp2, const bf16_t* __restrict__ fp1h,
    const bf16_t* __restrict__ W2sp, const float* __restrict__ bsum2,
    const float* __restrict__ c2r, float* __restrict__ c2w,
    bf16_t* __restrict__ h2w, float* __restrict__ G1h, float* __restrict__ hwp)
{
    const int nb = blockIdx.x, tid = threadIdx.x;
    const int w = tid >> 6, l = tid & 63;
    const int l15 = l & 15, koff = (l >> 4) * 8;
    __shared__ bf16_t h2t[64 * 16];   // 2 KB: h2(t+1) strip, bf16

    // ---- G1h(t+1) for this strip (kf 0..15, K=512 over h1(t+1)) ----
    {
        const int arow = w * 16 + l15;
        const bf16_t* ap = h1n + arow * 512 + koff;
        const bf16_t* wp = fp1h + (size_t)nb * 16 * 2048 + l * 8;
        f32x4 acc[4] = {};
#pragma unroll
        for (int kf = 0; kf < 16; ++kf) {
            bf16x8 a8 = *(const bf16x8*)&ap[kf * 32];
            const bf16_t* wk = wp + (size_t)kf * 2048;
#pragma unroll
            for (int s = 0; s < 4; ++s) {
                bf16x8 w8 = *(const bf16x8*)&wk[s * 512];
                acc[s] = __builtin_amdgcn_mfma_f32_16x16x32_bf16(a8, w8, acc[s], 0, 0, 0);
            }
        }
        const int rb = w * 16 + ((l >> 4) << 2);
        const int d = nb * 16 + l15;
#pragma unroll
        for (int s = 0; s < 4; ++s)
#pragma unroll
            for (int j = 0; j < 4; ++j)
                G1h[(rb + j) * 2048 + s * 512 + d] = acc[s][j];
    }

    // ---- gates2 full-K + pw2 (r8-r10-verified body) ----
    {
        const int arow = w * 16 + l15;
        f32x4 acc[4] = {};
        const bf16_t* wp = fp2 + (size_t)nb * 32 * 2048 + l * 8;
        {   // h1 part: kf 0..15
            const bf16_t* ap = h1n + arow * 512 + koff;
            for (int kf = 0; kf < 16; ++kf) {
                bf16x8 a8 = *(const bf16x8*)&ap[kf * 32];
                const bf16_t* wk = wp + (size_t)kf * 2048;
#pragma unroll
                for (int s = 0; s < 4; ++s) {
                    bf16x8 w8 = *(const bf16x8*)&wk[s * 512];
                    acc[s] = __builtin_amdgcn_mfma_f32_16x16x32_bf16(a8, w8, acc[s], 0, 0, 0);
                }
            }
        }
        {   // h2 part: kf 16..31
            const bf16_t* ap = h2r + arow * 512 + koff;
            for (int kf = 0; kf < 16; ++kf) {
                bf16x8 a8 = *(const bf16x8*)&ap[kf * 32];
                const bf16_t* wk = wp + (size_t)(16 + kf) * 2048;
#pragma unroll
                for (int s = 0; s < 4; ++s) {
                    bf16x8 w8 = *(const bf16x8*)&wk[s * 512];
                    acc[s] = __builtin_amdgcn_mfma_f32_16x16x32_bf16(a8, w8, acc[s], 0, 0, 0);
                }
            }
        }
        const int rb = w * 16 + ((l >> 4) << 2);
        const int d = nb * 16 + l15;
#pragma unroll
        for (int j = 0; j < 4; ++j) {
            int row = rb + j;
            float gi = acc[0][j] + bsum2[d];
            float gf = acc[1][j] + bsum2[512 + d];
            float gg = acc[2][j] + bsum2[1024 + d];
            float go = acc[3][j] + bsum2[1536 + d];
            float cn = sigf(gf) * c2r[row * 512 + d] + sigf(gi) * tanhf(gg);
            c2w[row * 512 + d] = cn;
            bf16_t hb = (bf16_t)(sigf(go) * tanhf(cn));
            h2w[row * 512 + d] = hb;
            h2t[row * 16 + l15] = hb;      // stage strip for hwp MFMA
        }
    }
    __syncthreads();

    // ---- hwp[nb][b][a]: h2strip (M=64, K=16 zero-padded to 32) @ W2sp ----
    {
        bf16x8 a8 = {};
        if ((l >> 4) < 2) a8 = *(const bf16x8*)&h2t[(w * 16 + l15) * 16 + koff];
        float* hp = hwp + (size_t)nb * SL;
        const int row = w * 16 + (l >> 4) * 4;
        for (int nt = 0; nt < 32; ++nt) {
            bf16x8 b8 = *(const bf16x8*)&W2sp[((size_t)(nb * 32 + nt) * 64 + l) * 8];
            f32x4 acc = {};
            acc = __builtin_amdgcn_mfma_f32_16x16x32_bf16(a8, b8, acc, 0, 0, 0);
            const int col = nt * 16 + l15;
#pragma unroll
            for (int j = 0; j < 4; ++j)
                hp[(row + j) * 512 + col] = acc[j];
        }
    }
}

// ---------------------------------------------------------------------------
extern "C" void kernel_launch(void* const* d_in, const int* in_sizes, int n_in,
                              void* d_out, int out_size, void* d_ws, size_t ws_size,
                              hipStream_t stream)
{
    const float* features = (const float*)d_in[0];
    const int*   captions = (const int*)d_in[1];
    const float* emb   = (const float*)d_in[2];
    const float* W1    = (const float*)d_in[3];
    const float* b1    = (const float*)d_in[4];
    const float* W2    = (const float*)d_in[5];
    const float* b2    = (const float*)d_in[6];
    const float* V     = (const float*)d_in[7];
    const float* bV    = (const float*)d_in[8];
    const float* W_ih1 = (const float*)d_in[9];
    const float* W_hh1 = (const float*)d_in[10];
    const float* b_ih1 = (const float*)d_in[11];
    const float* b_hh1 = (const float*)d_in[12];
    const float* W_ih2 = (const float*)d_in[13];
    const float* W_hh2 = (const float*)d_in[14];
    const float* b_ih2 = (const float*)d_in[15];
    const float* b_hh2 = (const float*)d_in[16];
    const float* fc_W  = (const float*)d_in[17];
    const float* fc_b  = (const float*)d_in[18];
    float* out = (float*)d_out;

    char* ws = (char*)d_ws;
    size_t off = 0;
    auto alloc = [&](size_t nbytes) {
        char* pp = ws + off;
        off = (off + nbytes + 255) & ~(size_t)255;
        return pp;
    };
    bf16_t* featb  = (bf16_t*)alloc(3136L * 2048 * 2);   // 12.8 MB
    bf16_t* fW1b   = (bf16_t*)alloc(3136L * 512 * 2);    // 3.2 MB
    bf16_t* F1g    = (bf16_t*)alloc(3136L * 2048 * 2);   // 12.8 MB
    bf16_t* W2sp   = (bf16_t*)alloc(32L * 32 * 64 * 8 * 2); // 1.0 MB
    bf16_t* fp1h   = (bf16_t*)alloc(32L * 16 * 2048 * 2);   // 2.1 MB
    bf16_t* fp2    = (bf16_t*)alloc(2048L * 1024 * 2);   // 4.2 MB
    bf16_t* fcWb   = (bf16_t*)alloc((size_t)VPAD * 512 * 2); // 10.5 MB
    bf16_t* xgb    = (bf16_t*)alloc(1920L * 256 * 2);
    bf16_t* xembb  = (bf16_t*)alloc(1920L * 2048 * 2);   // 7.9 MB
    float*  bsum1  = (float*)alloc(2048 * 4);
    float*  bsum2  = (float*)alloc(2048 * 4);
    float*  hwp    = (float*)alloc(32L * SL * 4);        // 4.0 MB
    float*  G1h    = (float*)alloc(64L * 2048 * 4);      // 0.5 MB
    bf16_t* h1s    = (bf16_t*)alloc((size_t)(T_ + 1) * SL * 2);
    bf16_t* h2s    = (bf16_t*)alloc((size_t)(T_ + 1) * SL * 2);
    float*  c1s    = (float*)alloc(2L * SL * 4);
    float*  c2s    = (float*)alloc(2L * SL * 4);
    // total ~64 MB (< proven 68.5 MB)

    prep_k<<<4096, 256, 0, stream>>>(
        b_ih1, b_hh1, bsum1, b_ih2, b_hh2, bsum2,
        W2, W2sp, W_hh1, fp1h, W_ih2, W_hh2, fp2, fc_W, fcWb,
        features, featb, captions, emb, xgb,
        h1s, h2s, c1s, c2s, hwp, G1h);

    // fW1b = featb @ W1^T + b1           [3136 x 512], K=2048
    mm_f32b<<<dim3(ATT / 64, 3136 / 64), 256, 0, stream>>>(
        featb, ENC, W1, ENC, 0, b1, fW1b, ATT, ENC);
    // xembb = xgb @ Wih1[:, :256]^T + bsum1   [1920 x 2048], K=256
    mm_f32b<<<dim3(G4 / 64, (T_ * B_) / 64), 256, 0, stream>>>(
        xgb, EMBED, W_ih1, EMBED + ENC, 0, bsum1, xembb, G4, EMBED);
    // F1g = featb @ Wih1[:, 256:2304]^T   [3136 x 2048], K=2048 (no bias)
    mm_f32b<<<dim3(G4 / 64, 3136 / 64), 256, 0, stream>>>(
        featb, ENC, W_ih1, EMBED + ENC, EMBED, nullptr, F1g, G4, ENC);

    for (int t = 0; t < T_; ++t) {
        attn1_k<<<B_, 256, 0, stream>>>(
            hwp, b2, fW1b, V, bV, F1g,
            xembb + (size_t)t * B_ * G4, G1h,
            c1s + (size_t)(t & 1) * SL, c1s + (size_t)((t + 1) & 1) * SL,
            h1s + (size_t)(t + 1) * SL);
        gate2_k<<<32, 256, 0, stream>>>(
            h1s + (size_t)(t + 1) * SL, h2s + (size_t)t * SL,
            fp2, fp1h, W2sp, bsum2,
            c2s + (size_t)(t & 1) * SL, c2s + (size_t)((t + 1) & 1) * SL,
            h2s + (size_t)(t + 1) * SL, G1h, hwp);
    }

    // out = h2(1..30) @ fc_W^T + fc_b  (f32 out, row remap t*64+b -> b*T+t)
    mm_fc<<<dim3(VPAD / 64, (T_ * B_) / 64), 256, 0, stream>>>(
        h2s + SL, DEC, fcWb, DEC, fc_b, out, VOCAB, VOCAB, DEC);
}

// Round 12
// 1391.707 us; speedup vs baseline: 3.5161x; 1.8182x over previous
//
#include <hip/hip_runtime.h>
#include <math.h>

#define VOCAB 10000
#define VPAD  10240   // padded so fc n-tile -> XCD map is stable (bid%8)
#define EMBED 256
#define ENC   2048
#define DEC   512
#define ATT   512
#define B_    64
#define P_    49
#define T_    30
#define G4    2048   // 4*DEC
#define SL    32768  // one state slice = B_*DEC (= 64*512)

typedef __bf16 bf16_t;
typedef bf16_t bf16x8 __attribute__((ext_vector_type(8)));
typedef float  f32x4  __attribute__((ext_vector_type(4)));

__device__ __forceinline__ float sigf(float x) { return 1.f / (1.f + expf(-x)); }

// ---------------------------------------------------------------------------
// One-time prep. NO barriers/atomics — all cross-block sync is kernel
// boundaries (r10/r11 PM: in-kernel barrier ~25us, coop sync ~70us, kernel
// boundary ~9us on this chip). Packings (verified r5-r11):
//  fp1h[((nb*16+kf)*4+s)*512+l*8+j] = W_hh1[s*512+nb*16+(l&15)][kf*32+(l>>4)*8+j]
//  fp2 same with 32 kf (kf<16: Wih2, kf>=16: Whh2).
//  W2sp[((nb*32+nt)*64+lq)*8+j]: B-frag of W2 col-strip nb, K=32 zero-padded.
// Zeroed per call: h1s/h2s slice0, c slices, hwp, G1h.
// ---------------------------------------------------------------------------
__global__ void prep_k(
    const float* __restrict__ b_ih1, const float* __restrict__ b_hh1, float* __restrict__ bsum1,
    const float* __restrict__ b_ih2, const float* __restrict__ b_hh2, float* __restrict__ bsum2,
    const float* __restrict__ W2,    bf16_t* __restrict__ W2sp,
    const float* __restrict__ W_hh1, bf16_t* __restrict__ fp1h,
    const float* __restrict__ W_ih2, const float* __restrict__ W_hh2, bf16_t* __restrict__ fp2,
    const float* __restrict__ fc_W,  bf16_t* __restrict__ fcWb,
    const float* __restrict__ features, bf16_t* __restrict__ featb,
    const int* __restrict__ caps, const float* __restrict__ emb, bf16_t* __restrict__ xgb,
    bf16_t* __restrict__ h1s0, bf16_t* __restrict__ h2s0,
    float* __restrict__ c1s0, float* __restrict__ c2s0,
    float* __restrict__ hwp, float* __restrict__ G1h)
{
    long stride = (long)gridDim.x * blockDim.x;
    long i0 = (long)blockIdx.x * blockDim.x + threadIdx.x;
    for (long i = i0; i < SL; i += stride) {
        h1s0[i] = (bf16_t)0.f; h2s0[i] = (bf16_t)0.f;
        c1s0[i] = 0.f; c2s0[i] = 0.f;
    }
    for (long i = i0; i < 32L * SL; i += stride) hwp[i] = 0.f;
    for (long i = i0; i < 64L * 2048; i += stride) G1h[i] = 0.f;
    for (long i = i0; i < 2048; i += stride) {
        bsum1[i] = b_ih1[i] + b_hh1[i];
        bsum2[i] = b_ih2[i] + b_hh2[i];
    }
    for (long i = i0; i < 32L * 32 * 64 * 8; i += stride) {  // W2sp (1 MB)
        long j8 = i & 7, lq = (i >> 3) & 63, nt = (i >> 9) & 31, nb = i >> 14;
        long k = (lq >> 4) * 8 + j8;
        long a = nt * 16 + (lq & 15);
        W2sp[i] = (bf16_t)(k < 16 ? W2[a * 512 + nb * 16 + k] : 0.f);
    }
    for (long i = i0; i < 32L * 16 * 2048; i += stride) { // fp1h (Whh1 part)
        long j8 = i & 7, lq = (i >> 3) & 63, s = (i >> 9) & 3, nk = i >> 11;
        long kf = nk & 15, nb = nk >> 4;
        long c = s * 512 + nb * 16 + (lq & 15);
        long k = kf * 32 + (lq >> 4) * 8 + j8;
        fp1h[i] = (bf16_t)W_hh1[c * 512 + k];
    }
    for (long i = i0; i < 2048L * 1024; i += stride) { // fp2
        long j8 = i & 7, lq = (i >> 3) & 63, s = (i >> 9) & 3, nk = i >> 11;
        long kf = nk & 31, nb = nk >> 5;
        long c = s * 512 + nb * 16 + (lq & 15);
        long k = kf * 32 + (lq >> 4) * 8 + j8;
        fp2[i] = (bf16_t)(k < 512 ? W_ih2[c * 512 + k] : W_hh2[c * 512 + (k - 512)]);
    }
    for (long i = i0; i < (long)VPAD * 512; i += stride) {
        long r = i >> 9;
        fcWb[i] = (bf16_t)(r < VOCAB ? fc_W[i] : 0.f);
    }
    for (long i = i0; i < 3136L * 2048; i += stride) featb[i] = (bf16_t)features[i];
    for (long i = i0; i < 1920L * 256; i += stride) {
        long row = i >> 8, e = i & 255;
        long tq = row >> 6, b = row & 63;
        int cap = caps[b * T_ + tq];
        xgb[i] = (bf16_t)emb[(long)cap * 256 + e];
    }
}

// ---------------------------------------------------------------------------
// mm_f32b: C[M,N](bf16) = A(bf16)[M,K] @ B(f32,strided)[N,K]^T (+bias).
// Verified r10/r11.
// ---------------------------------------------------------------------------
__global__ __launch_bounds__(256) void mm_f32b(
    const bf16_t* __restrict__ A, int lda,
    const float* __restrict__ Bw, int ldb, int boff,
    const float* __restrict__ bias,
    bf16_t* __restrict__ outB, int ldo, int K)
{
    __shared__ bf16_t Apad[64][72];
    __shared__ bf16_t Bpad[64][72];
    const int bn = blockIdx.x * 64, bm = blockIdx.y * 64;
    const int tid = threadIdx.x;
    const int w = tid >> 6, l = tid & 63;
    f32x4 acc[4] = {};

    for (int k0 = 0; k0 < K; k0 += 64) {
        for (int c = tid; c < 512; c += 256) {
            int row = c >> 3, q = c & 7;
            *(bf16x8*)&Apad[row][q * 8] = *(const bf16x8*)&A[(size_t)(bm + row) * lda + k0 + q * 8];
            const float* bs = &Bw[(size_t)(bn + row) * ldb + boff + k0 + q * 8];
            float4 f0 = *(const float4*)bs;
            float4 f1 = *(const float4*)(bs + 4);
            bf16x8 v;
            v[0] = (bf16_t)f0.x; v[1] = (bf16_t)f0.y; v[2] = (bf16_t)f0.z; v[3] = (bf16_t)f0.w;
            v[4] = (bf16_t)f1.x; v[5] = (bf16_t)f1.y; v[6] = (bf16_t)f1.z; v[7] = (bf16_t)f1.w;
            *(bf16x8*)&Bpad[row][q * 8] = v;
        }
        __syncthreads();
#pragma unroll
        for (int ks = 0; ks < 2; ++ks) {
            bf16x8 a8 = *(const bf16x8*)&Apad[w * 16 + (l & 15)][ks * 32 + (l >> 4) * 8];
#pragma unroll
            for (int nf = 0; nf < 4; ++nf) {
                bf16x8 b8 = *(const bf16x8*)&Bpad[nf * 16 + (l & 15)][ks * 32 + (l >> 4) * 8];
                acc[nf] = __builtin_amdgcn_mfma_f32_16x16x32_bf16(a8, b8, acc[nf], 0, 0, 0);
            }
        }
        __syncthreads();
    }

    int rbase = bm + w * 16 + (l >> 4) * 4;
    int cl = l & 15;
#pragma unroll
    for (int nf = 0; nf < 4; ++nf) {
        int col = bn + nf * 16 + cl;
        float bv = bias ? bias[col] : 0.f;
#pragma unroll
        for (int j = 0; j < 4; ++j)
            outB[(size_t)(rbase + j) * ldo + col] = (bf16_t)(acc[nf][j] + bv);
    }
}

// ---------------------------------------------------------------------------
// fc GEMM (bf16 A/B, f32 out, row remap + N guard) — verified r6-r11.
// ---------------------------------------------------------------------------
__global__ __launch_bounds__(256) void mm_fc(
    const bf16_t* __restrict__ A, int lda,
    const bf16_t* __restrict__ Bw, int ldb,
    const float* __restrict__ bias,
    float* __restrict__ outF, int ldo, int N, int K)
{
    __shared__ bf16_t Apad[64][72];
    __shared__ bf16_t Bpad[64][72];
    const int bn = blockIdx.x * 64, bm = blockIdx.y * 64;
    const int tid = threadIdx.x;
    const int w = tid >> 6, l = tid & 63;
    f32x4 acc[4] = {};

    for (int k0 = 0; k0 < K; k0 += 64) {
        for (int c = tid; c < 512; c += 256) {
            int row = c >> 3, q = c & 7;
            *(bf16x8*)&Apad[row][q * 8] = *(const bf16x8*)&A[(size_t)(bm + row) * lda + k0 + q * 8];
            *(bf16x8*)&Bpad[row][q * 8] = *(const bf16x8*)&Bw[(size_t)(bn + row) * ldb + k0 + q * 8];
        }
        __syncthreads();
#pragma unroll
        for (int ks = 0; ks < 2; ++ks) {
            bf16x8 a8 = *(const bf16x8*)&Apad[w * 16 + (l & 15)][ks * 32 + (l >> 4) * 8];
#pragma unroll
            for (int nf = 0; nf < 4; ++nf) {
                bf16x8 b8 = *(const bf16x8*)&Bpad[nf * 16 + (l & 15)][ks * 32 + (l >> 4) * 8];
                acc[nf] = __builtin_amdgcn_mfma_f32_16x16x32_bf16(a8, b8, acc[nf], 0, 0, 0);
            }
        }
        __syncthreads();
    }

    int rbase = bm + w * 16 + (l >> 4) * 4;
    int cl = l & 15;
#pragma unroll
    for (int nf = 0; nf < 4; ++nf) {
        int col = bn + nf * 16 + cl;
#pragma unroll
        for (int j = 0; j < 4; ++j) {
            int row = rbase + j;
            if (col < N) {
                int orow = (row & 63) * T_ + (row >> 6);  // t*64+b -> b*T+t
                outF[(size_t)orow * ldo + col] = acc[nf][j] + bias[col];
            }
        }
    }
}

// ===========================================================================
// STEP KERNEL 1 — per-batch (64 blocks x 256 thr, no cross-block deps):
//  hw[b] = b2 + sum_nb hwp[b][nb][:]   (contiguous 64KB/block — r11 PM fix)
//  scores + softmax (r7-verified body)
//  g1pre = sum_p wn[p]*F1g[b][p][:] via bf16x8 full row (r7-ctx-loop clone;
//          r11's bf16x2 form issued 4x the loads)
//  pw1: gates1 = xembb + g1pre + G1h[b] -> LSTM1 -> h1(t+1)[b], c1
// ===========================================================================
__global__ __launch_bounds__(256) void attn1_k(
    const float* __restrict__ hwp, const float* __restrict__ b2,
    const bf16_t* __restrict__ fW1b, const float* __restrict__ V,
    const float* __restrict__ bV, const bf16_t* __restrict__ F1g,
    const bf16_t* __restrict__ xeb, const float* __restrict__ G1h,
    const float* __restrict__ c1r, float* __restrict__ c1w,
    bf16_t* __restrict__ h1w)
{
    const int b = blockIdx.x, tid = threadIdx.x;
    const int w = tid >> 6, l = tid & 63;
    __shared__ float hw[512];
    __shared__ float sc[64];
    __shared__ float wn[64];
    __shared__ float gsum[2048];

    {   // hw reduce over 32 partials (contiguous [b][nb][a] layout)
        float a0 = b2[2 * tid], a1 = b2[2 * tid + 1];
        const float* hp = hwp + (size_t)b * 16384 + 2 * tid;
#pragma unroll 8
        for (int nb = 0; nb < 32; ++nb) {
            float2 v = *(const float2*)&hp[nb * 512];
            a0 += v.x; a1 += v.y;
        }
        hw[2 * tid] = a0; hw[2 * tid + 1] = a1;
    }
    __syncthreads();
    {   // scores
        float hwr[8], Vr[8];
#pragma unroll
        for (int i = 0; i < 8; ++i) { hwr[i] = hw[l * 8 + i]; Vr[i] = V[l * 8 + i]; }
        for (int pq = w; pq < P_; pq += 4) {
            bf16x8 f8 = *(const bf16x8*)&fW1b[(size_t)(b * P_ + pq) * 512 + l * 8];
            float s = 0.f;
#pragma unroll
            for (int i = 0; i < 8; ++i) s += tanhf((float)f8[i] + hwr[i]) * Vr[i];
#pragma unroll
            for (int o = 32; o; o >>= 1) s += __shfl_xor(s, o);
            if (l == 0) sc[pq] = s + bV[0];
        }
    }
    __syncthreads();
    {   // softmax
        float m = -1e30f;
        for (int q = 0; q < P_; ++q) m = fmaxf(m, sc[q]);
        float ss = 0.f;
        for (int q = 0; q < P_; ++q) ss += expf(sc[q] - m);
        if (tid < P_) wn[tid] = expf(sc[tid] - m) / ss;
    }
    __syncthreads();
    {   // g1pre: full-row bf16x8 (thread owns gates [tid*8, tid*8+8))
        float acc[8] = {};
        const bf16_t* fg = F1g + (size_t)b * P_ * 2048 + tid * 8;
#pragma unroll 7
        for (int q = 0; q < P_; ++q) {
            bf16x8 f8 = *(const bf16x8*)&fg[(size_t)q * 2048];
            float wq = wn[q];
#pragma unroll
            for (int i = 0; i < 8; ++i) acc[i] += wq * (float)f8[i];
        }
#pragma unroll
        for (int i = 0; i < 8; ++i) gsum[tid * 8 + i] = acc[i];
    }
    __syncthreads();
    {   // pw1 (batch-row-local; body verified r11)
        const bf16_t* xb = xeb + (size_t)b * G4;
        const float* gh = G1h + b * 2048;
#pragma unroll
        for (int u = 0; u < 2; ++u) {
            int d = 2 * tid + u;
            float gi = (float)xb[d]        + gsum[d]        + gh[d];
            float gf = (float)xb[512 + d]  + gsum[512 + d]  + gh[512 + d];
            float gg = (float)xb[1024 + d] + gsum[1024 + d] + gh[1024 + d];
            float go = (float)xb[1536 + d] + gsum[1536 + d] + gh[1536 + d];
            int idx = b * 512 + d;
            float cn = sigf(gf) * c1r[idx] + sigf(gi) * tanhf(gg);
            c1w[idx] = cn;
            h1w[idx] = (bf16_t)(sigf(go) * tanhf(cn));
        }
    }
}

// ===========================================================================
// STEP KERNEL 2 — 64 blocks x 512 thr (8 waves), two independent ranges:
//  bid 0..31 (nb=bid): gates2 8-wave K-split + LDS reduce (r7 g2pw_k body,
//    verified) -> pw2 -> h2(t+1) strip; then hwp tail (16 nt per wave,
//    K=16-zero-padded MFMA vs W2sp — r11-verified math, [b][nb][a] layout).
//  bid 32..63 (nb=bid-32): G1h(t+1) strip with the same 8-wave K-split
//    (r10/r11-verified math, chain halved).
// ===========================================================================
__global__ __launch_bounds__(512) void gate2_k(
    const bf16_t* __restrict__ h1n, const bf16_t* __restrict__ h2r,
    const bf16_t* __restrict__ fp2, const bf16_t* __restrict__ fp1h,
    const bf16_t* __restrict__ W2sp, const float* __restrict__ bsum2,
    const float* __restrict__ c2r, float* __restrict__ c2w,
    bf16_t* __restrict__ h2w, float* __restrict__ G1h, float* __restrict__ hwp)
{
    const int bid = blockIdx.x, tid = threadIdx.x;
    const int w = tid >> 6, l = tid & 63;
    const int l15 = l & 15, koff = (l >> 4) * 8;
    const int mt = w & 3, kh = w >> 2;
    __shared__ float red[2][4][4][256];   // 32 KB
    __shared__ bf16_t h2t[64 * 16];       // 2 KB

    if (bid < 32) {
        const int nb = bid;
        // ---- gates2: wave (mt, kh); kh=0 -> h1(t+1) K-half, kh=1 -> h2(t) ----
        {
            const int arow = mt * 16 + l15;
            const bf16_t* ap = (kh == 0 ? h1n : h2r) + arow * 512 + koff;
            const bf16_t* wp = fp2 + ((size_t)nb * 32 + kh * 16) * 2048 + l * 8;
            f32x4 acc[4] = {};
#pragma unroll
            for (int kf = 0; kf < 16; ++kf) {
                bf16x8 a8 = *(const bf16x8*)&ap[kf * 32];
                const bf16_t* wk = wp + (size_t)kf * 2048;
#pragma unroll
                for (int s = 0; s < 4; ++s) {
                    bf16x8 w8 = *(const bf16x8*)&wk[s * 512];
                    acc[s] = __builtin_amdgcn_mfma_f32_16x16x32_bf16(a8, w8, acc[s], 0, 0, 0);
                }
            }
#pragma unroll
            for (int s = 0; s < 4; ++s) *(f32x4*)&red[kh][mt][s][l * 4] = acc[s];
        }
        __syncthreads();
        if (w < 4) {
            const int d = nb * 16 + l15;
            const int rb = w * 16 + ((l >> 4) << 2);
            f32x4 v[4];
#pragma unroll
            for (int s = 0; s < 4; ++s)
                v[s] = *(const f32x4*)&red[0][w][s][l * 4] + *(const f32x4*)&red[1][w][s][l * 4];
#pragma unroll
            for (int j = 0; j < 4; ++j) {
                int row = rb + j;
                float gi = v[0][j] + bsum2[d];
                float gf = v[1][j] + bsum2[512 + d];
                float gg = v[2][j] + bsum2[1024 + d];
                float go = v[3][j] + bsum2[1536 + d];
                float cn = sigf(gf) * c2r[row * 512 + d] + sigf(gi) * tanhf(gg);
                c2w[row * 512 + d] = cn;
                bf16_t hb = (bf16_t)(sigf(go) * tanhf(cn));
                h2w[row * 512 + d] = hb;
                h2t[row * 16 + l15] = hb;
            }
        }
        __syncthreads();
        // ---- hwp tail: wave (mt, kh) -> M-tile mt, nt-half kh (16 nt each) ----
        {
            bf16x8 a8 = {};
            if ((l >> 4) < 2) a8 = *(const bf16x8*)&h2t[(mt * 16 + l15) * 16 + koff];
            const int row0 = mt * 16 + (l >> 4) * 4;
            for (int q = 0; q < 16; ++q) {
                int nt = kh * 16 + q;
                bf16x8 b8 = *(const bf16x8*)&W2sp[((size_t)(nb * 32 + nt) * 64 + l) * 8];
                f32x4 acc2 = {};
                acc2 = __builtin_amdgcn_mfma_f32_16x16x32_bf16(a8, b8, acc2, 0, 0, 0);
                const int col = nt * 16 + l15;
#pragma unroll
                for (int j = 0; j < 4; ++j)
                    hwp[(size_t)(row0 + j) * 16384 + nb * 512 + col] = acc2[j];
            }
        }
    } else {
        const int nb = bid - 32;
        // ---- G1h(t+1): wave (mt, kh); kh splits kf 0..7 / 8..15 ----
        {
            const int arow = mt * 16 + l15;
            const bf16_t* ap = h1n + arow * 512 + kh * 256 + koff;
            const bf16_t* wp = fp1h + ((size_t)nb * 16 + kh * 8) * 2048 + l * 8;
            f32x4 acc[4] = {};
#pragma unroll
            for (int kf = 0; kf < 8; ++kf) {
                bf16x8 a8 = *(const bf16x8*)&ap[kf * 32];
                const bf16_t* wk = wp + (size_t)kf * 2048;
#pragma unroll
                for (int s = 0; s < 4; ++s) {
                    bf16x8 w8 = *(const bf16x8*)&wk[s * 512];
                    acc[s] = __builtin_amdgcn_mfma_f32_16x16x32_bf16(a8, w8, acc[s], 0, 0, 0);
                }
            }
#pragma unroll
            for (int s = 0; s < 4; ++s) *(f32x4*)&red[kh][mt][s][l * 4] = acc[s];
        }
        __syncthreads();
        if (w < 4) {
            const int d = nb * 16 + l15;
            const int rb = w * 16 + ((l >> 4) << 2);
#pragma unroll
            for (int s = 0; s < 4; ++s) {
                f32x4 v = *(const f32x4*)&red[0][w][s][l * 4] + *(const f32x4*)&red[1][w][s][l * 4];
#pragma unroll
                for (int j = 0; j < 4; ++j)
                    G1h[(rb + j) * 2048 + s * 512 + d] = v[j];
            }
        }
    }
}

// ---------------------------------------------------------------------------
extern "C" void kernel_launch(void* const* d_in, const int* in_sizes, int n_in,
                              void* d_out, int out_size, void* d_ws, size_t ws_size,
                              hipStream_t stream)
{
    const float* features = (const float*)d_in[0];
    const int*   captions = (const int*)d_in[1];
    const float* emb   = (const float*)d_in[2];
    const float* W1    = (const float*)d_in[3];
    const float* b1    = (const float*)d_in[4];
    const float* W2    = (const float*)d_in[5];
    const float* b2    = (const float*)d_in[6];
    const float* V     = (const float*)d_in[7];
    const float* bV    = (const float*)d_in[8];
    const float* W_ih1 = (const float*)d_in[9];
    const float* W_hh1 = (const float*)d_in[10];
    const float* b_ih1 = (const float*)d_in[11];
    const float* b_hh1 = (const float*)d_in[12];
    const float* W_ih2 = (const float*)d_in[13];
    const float* W_hh2 = (const float*)d_in[14];
    const float* b_ih2 = (const float*)d_in[15];
    const float* b_hh2 = (const float*)d_in[16];
    const float* fc_W  = (const float*)d_in[17];
    const float* fc_b  = (const float*)d_in[18];
    float* out = (float*)d_out;

    char* ws = (char*)d_ws;
    size_t off = 0;
    auto alloc = [&](size_t nbytes) {
        char* pp = ws + off;
        off = (off + nbytes + 255) & ~(size_t)255;
        return pp;
    };
    bf16_t* featb  = (bf16_t*)alloc(3136L * 2048 * 2);   // 12.8 MB
    bf16_t* fW1b   = (bf16_t*)alloc(3136L * 512 * 2);    // 3.2 MB
    bf16_t* F1g    = (bf16_t*)alloc(3136L * 2048 * 2);   // 12.8 MB
    bf16_t* W2sp   = (bf16_t*)alloc(32L * 32 * 64 * 8 * 2); // 1.0 MB
    bf16_t* fp1h   = (bf16_t*)alloc(32L * 16 * 2048 * 2);   // 2.1 MB
    bf16_t* fp2    = (bf16_t*)alloc(2048L * 1024 * 2);   // 4.2 MB
    bf16_t* fcWb   = (bf16_t*)alloc((size_t)VPAD * 512 * 2); // 10.5 MB
    bf16_t* xgb    = (bf16_t*)alloc(1920L * 256 * 2);
    bf16_t* xembb  = (bf16_t*)alloc(1920L * 2048 * 2);   // 7.9 MB
    float*  bsum1  = (float*)alloc(2048 * 4);
    float*  bsum2  = (float*)alloc(2048 * 4);
    float*  hwp    = (float*)alloc(32L * SL * 4);        // 4.0 MB, [b][nb][a]
    float*  G1h    = (float*)alloc(64L * 2048 * 4);      // 0.5 MB
    bf16_t* h1s    = (bf16_t*)alloc((size_t)(T_ + 1) * SL * 2);
    bf16_t* h2s    = (bf16_t*)alloc((size_t)(T_ + 1) * SL * 2);
    float*  c1s    = (float*)alloc(2L * SL * 4);
    float*  c2s    = (float*)alloc(2L * SL * 4);
    // total ~64 MB (< proven 68.5 MB)

    prep_k<<<4096, 256, 0, stream>>>(
        b_ih1, b_hh1, bsum1, b_ih2, b_hh2, bsum2,
        W2, W2sp, W_hh1, fp1h, W_ih2, W_hh2, fp2, fc_W, fcWb,
        features, featb, captions, emb, xgb,
        h1s, h2s, c1s, c2s, hwp, G1h);

    // fW1b = featb @ W1^T + b1           [3136 x 512], K=2048
    mm_f32b<<<dim3(ATT / 64, 3136 / 64), 256, 0, stream>>>(
        featb, ENC, W1, ENC, 0, b1, fW1b, ATT, ENC);
    // xembb = xgb @ Wih1[:, :256]^T + bsum1   [1920 x 2048], K=256
    mm_f32b<<<dim3(G4 / 64, (T_ * B_) / 64), 256, 0, stream>>>(
        xgb, EMBED, W_ih1, EMBED + ENC, 0, bsum1, xembb, G4, EMBED);
    // F1g = featb @ Wih1[:, 256:2304]^T   [3136 x 2048], K=2048 (no bias)
    mm_f32b<<<dim3(G4 / 64, 3136 / 64), 256, 0, stream>>>(
        featb, ENC, W_ih1, EMBED + ENC, EMBED, nullptr, F1g, G4, ENC);

    for (int t = 0; t < T_; ++t) {
        attn1_k<<<B_, 256, 0, stream>>>(
            hwp, b2, fW1b, V, bV, F1g,
            xembb + (size_t)t * B_ * G4, G1h,
            c1s + (size_t)(t & 1) * SL, c1s + (size_t)((t + 1) & 1) * SL,
            h1s + (size_t)(t + 1) * SL);
        gate2_k<<<64, 512, 0, stream>>>(
            h1s + (size_t)(t + 1) * SL, h2s + (size_t)t * SL,
            fp2, fp1h, W2sp, bsum2,
            c2s + (size_t)(t & 1) * SL, c2s + (size_t)((t + 1) & 1) * SL,
            h2s + (size_t)(t + 1) * SL, G1h, hwp);
    }

    // out = h2(1..30) @ fc_W^T + fc_b  (f32 out, row remap t*64+b -> b*T+t)
    mm_fc<<<dim3(VPAD / 64, (T_ * B_) / 64), 256, 0, stream>>>(
        h2s + SL, DEC, fcWb, DEC, fc_b, out, VOCAB, VOCAB, DEC);
}

// Round 13
// 1139.773 us; speedup vs baseline: 4.2932x; 1.2210x over previous
//
#include <hip/hip_runtime.h>
#include <math.h>

#define VOCAB 10000
#define VPAD  10240   // padded so fc n-tile -> XCD map is stable (bid%8)
#define EMBED 256
#define ENC   2048
#define DEC   512
#define ATT   512
#define B_    64
#define P_    49
#define T_    30
#define G4    2048   // 4*DEC
#define SL    32768  // one state slice = B_*DEC (= 64*512)

typedef __bf16 bf16_t;
typedef bf16_t bf16x8 __attribute__((ext_vector_type(8)));
typedef float  f32x4  __attribute__((ext_vector_type(4)));

__device__ __forceinline__ float sigf(float x) { return 1.f / (1.f + expf(-x)); }

// ---------------------------------------------------------------------------
// One-time prep. NO barriers/atomics — all cross-block sync is kernel
// boundaries (r10-r12 PM: in-kernel barrier ~25us, coop sync ~70us, kernel
// boundary ~9us on this chip). Packings (verified r5-r12):
//  fp1h[((nb*16+kf)*4+s)*512+l*8+j] = W_hh1[s*512+nb*16+(l&15)][kf*32+(l>>4)*8+j]
//  fp2 same with 32 kf (kf<16: Wih2, kf>=16: Whh2).
//  W2sp[((nb*32+nt)*64+lq)*8+j]: B-frag of W2 col-strip nb, K=32 zero-padded.
// Zeroed per call: h1s/h2s slice0, c slices, hwp, G1h.
// (featb dropped in r13 — features feed GEMMs directly via f32 staging.)
// ---------------------------------------------------------------------------
__global__ void prep_k(
    const float* __restrict__ b_ih1, const float* __restrict__ b_hh1, float* __restrict__ bsum1,
    const float* __restrict__ b_ih2, const float* __restrict__ b_hh2, float* __restrict__ bsum2,
    const float* __restrict__ W2,    bf16_t* __restrict__ W2sp,
    const float* __restrict__ W_hh1, bf16_t* __restrict__ fp1h,
    const float* __restrict__ W_ih2, const float* __restrict__ W_hh2, bf16_t* __restrict__ fp2,
    const float* __restrict__ fc_W,  bf16_t* __restrict__ fcWb,
    const int* __restrict__ caps, const float* __restrict__ emb, bf16_t* __restrict__ xgb,
    bf16_t* __restrict__ h1s0, bf16_t* __restrict__ h2s0,
    float* __restrict__ c1s0, float* __restrict__ c2s0,
    float* __restrict__ hwp, float* __restrict__ G1h)
{
    long stride = (long)gridDim.x * blockDim.x;
    long i0 = (long)blockIdx.x * blockDim.x + threadIdx.x;
    for (long i = i0; i < SL; i += stride) {
        h1s0[i] = (bf16_t)0.f; h2s0[i] = (bf16_t)0.f;
        c1s0[i] = 0.f; c2s0[i] = 0.f;
    }
    for (long i = i0; i < 32L * SL; i += stride) hwp[i] = 0.f;
    for (long i = i0; i < 64L * 2048; i += stride) G1h[i] = 0.f;
    for (long i = i0; i < 2048; i += stride) {
        bsum1[i] = b_ih1[i] + b_hh1[i];
        bsum2[i] = b_ih2[i] + b_hh2[i];
    }
    for (long i = i0; i < 32L * 32 * 64 * 8; i += stride) {  // W2sp (1 MB)
        long j8 = i & 7, lq = (i >> 3) & 63, nt = (i >> 9) & 31, nb = i >> 14;
        long k = (lq >> 4) * 8 + j8;
        long a = nt * 16 + (lq & 15);
        W2sp[i] = (bf16_t)(k < 16 ? W2[a * 512 + nb * 16 + k] : 0.f);
    }
    for (long i = i0; i < 32L * 16 * 2048; i += stride) { // fp1h (Whh1 part)
        long j8 = i & 7, lq = (i >> 3) & 63, s = (i >> 9) & 3, nk = i >> 11;
        long kf = nk & 15, nb = nk >> 4;
        long c = s * 512 + nb * 16 + (lq & 15);
        long k = kf * 32 + (lq >> 4) * 8 + j8;
        fp1h[i] = (bf16_t)W_hh1[c * 512 + k];
    }
    for (long i = i0; i < 2048L * 1024; i += stride) { // fp2
        long j8 = i & 7, lq = (i >> 3) & 63, s = (i >> 9) & 3, nk = i >> 11;
        long kf = nk & 31, nb = nk >> 5;
        long c = s * 512 + nb * 16 + (lq & 15);
        long k = kf * 32 + (lq >> 4) * 8 + j8;
        fp2[i] = (bf16_t)(k < 512 ? W_ih2[c * 512 + k] : W_hh2[c * 512 + (k - 512)]);
    }
    for (long i = i0; i < (long)VPAD * 512; i += stride) {
        long r = i >> 9;
        fcWb[i] = (bf16_t)(r < VOCAB ? fc_W[i] : 0.f);
    }
    for (long i = i0; i < 1920L * 256; i += stride) {
        long row = i >> 8, e = i & 255;
        long tq = row >> 6, b = row & 63;
        int cap = caps[b * T_ + tq];
        xgb[i] = (bf16_t)emb[(long)cap * 256 + e];
    }
}

// ---------------------------------------------------------------------------
// mm3_k: the three prep GEMMs fused into ONE node (flattened grid, 2920 blk).
//  seg0 (392):  fW1b  = features(f32) @ W1^T + b1          M=3136 N=512  K=2048
//  seg1 (960):  xembb = xgb(bf16) @ Wih1[:,:256]^T + bsum1 M=1920 N=2048 K=256
//  seg2 (1568): F1g   = features(f32) @ Wih1[:,256:]^T     M=3136 N=2048 K=2048
// Body = r10-r12-verified mm_f32b core, + f32/bf16 A-staging branch.
// ---------------------------------------------------------------------------
__global__ __launch_bounds__(256) void mm3_k(
    const float* __restrict__ features, const bf16_t* __restrict__ xgb,
    const float* __restrict__ W1, const float* __restrict__ W_ih1,
    const float* __restrict__ b1, const float* __restrict__ bsum1,
    bf16_t* __restrict__ fW1b, bf16_t* __restrict__ xembb, bf16_t* __restrict__ F1g)
{
    int bid = blockIdx.x;
    const float* Af; const bf16_t* Ab = nullptr; int lda;
    const float* Bw; int ldb, boff;
    const float* bias; bf16_t* outB; int ldo, K, bn, bm;
    if (bid < 392) {
        Af = features; lda = ENC; Bw = W1; ldb = ENC; boff = 0;
        bias = b1; outB = fW1b; ldo = ATT; K = ENC;
        bn = (bid & 7) * 64; bm = (bid >> 3) * 64;
    } else if (bid < 1352) {
        int b2i = bid - 392;
        Af = nullptr; Ab = xgb; lda = EMBED; Bw = W_ih1; ldb = EMBED + ENC; boff = 0;
        bias = bsum1; outB = xembb; ldo = G4; K = EMBED;
        bn = (b2i & 31) * 64; bm = (b2i >> 5) * 64;
    } else {
        int b3i = bid - 1352;
        Af = features; lda = ENC; Bw = W_ih1; ldb = EMBED + ENC; boff = EMBED;
        bias = nullptr; outB = F1g; ldo = G4; K = ENC;
        bn = (b3i & 31) * 64; bm = (b3i >> 5) * 64;
    }

    __shared__ bf16_t Apad[64][72];
    __shared__ bf16_t Bpad[64][72];
    const int tid = threadIdx.x;
    const int w = tid >> 6, l = tid & 63;
    f32x4 acc[4] = {};

    for (int k0 = 0; k0 < K; k0 += 64) {
        for (int c = tid; c < 512; c += 256) {
            int row = c >> 3, q = c & 7;
            if (Af) {
                const float* as = &Af[(size_t)(bm + row) * lda + k0 + q * 8];
                float4 f0 = *(const float4*)as;
                float4 f1 = *(const float4*)(as + 4);
                bf16x8 v;
                v[0] = (bf16_t)f0.x; v[1] = (bf16_t)f0.y; v[2] = (bf16_t)f0.z; v[3] = (bf16_t)f0.w;
                v[4] = (bf16_t)f1.x; v[5] = (bf16_t)f1.y; v[6] = (bf16_t)f1.z; v[7] = (bf16_t)f1.w;
                *(bf16x8*)&Apad[row][q * 8] = v;
            } else {
                *(bf16x8*)&Apad[row][q * 8] = *(const bf16x8*)&Ab[(size_t)(bm + row) * lda + k0 + q * 8];
            }
            const float* bs = &Bw[(size_t)(bn + row) * ldb + boff + k0 + q * 8];
            float4 f0 = *(const float4*)bs;
            float4 f1 = *(const float4*)(bs + 4);
            bf16x8 v;
            v[0] = (bf16_t)f0.x; v[1] = (bf16_t)f0.y; v[2] = (bf16_t)f0.z; v[3] = (bf16_t)f0.w;
            v[4] = (bf16_t)f1.x; v[5] = (bf16_t)f1.y; v[6] = (bf16_t)f1.z; v[7] = (bf16_t)f1.w;
            *(bf16x8*)&Bpad[row][q * 8] = v;
        }
        __syncthreads();
#pragma unroll
        for (int ks = 0; ks < 2; ++ks) {
            bf16x8 a8 = *(const bf16x8*)&Apad[w * 16 + (l & 15)][ks * 32 + (l >> 4) * 8];
#pragma unroll
            for (int nf = 0; nf < 4; ++nf) {
                bf16x8 b8 = *(const bf16x8*)&Bpad[nf * 16 + (l & 15)][ks * 32 + (l >> 4) * 8];
                acc[nf] = __builtin_amdgcn_mfma_f32_16x16x32_bf16(a8, b8, acc[nf], 0, 0, 0);
            }
        }
        __syncthreads();
    }

    int rbase = bm + w * 16 + (l >> 4) * 4;
    int cl = l & 15;
#pragma unroll
    for (int nf = 0; nf < 4; ++nf) {
        int col = bn + nf * 16 + cl;
        float bv = bias ? bias[col] : 0.f;
#pragma unroll
        for (int j = 0; j < 4; ++j)
            outB[(size_t)(rbase + j) * ldo + col] = (bf16_t)(acc[nf][j] + bv);
    }
}

// ---------------------------------------------------------------------------
// fc GEMM (bf16 A/B, f32 out, row remap + N guard) — verified r6-r12.
// ---------------------------------------------------------------------------
__global__ __launch_bounds__(256) void mm_fc(
    const bf16_t* __restrict__ A, int lda,
    const bf16_t* __restrict__ Bw, int ldb,
    const float* __restrict__ bias,
    float* __restrict__ outF, int ldo, int N, int K)
{
    __shared__ bf16_t Apad[64][72];
    __shared__ bf16_t Bpad[64][72];
    const int bn = blockIdx.x * 64, bm = blockIdx.y * 64;
    const int tid = threadIdx.x;
    const int w = tid >> 6, l = tid & 63;
    f32x4 acc[4] = {};

    for (int k0 = 0; k0 < K; k0 += 64) {
        for (int c = tid; c < 512; c += 256) {
            int row = c >> 3, q = c & 7;
            *(bf16x8*)&Apad[row][q * 8] = *(const bf16x8*)&A[(size_t)(bm + row) * lda + k0 + q * 8];
            *(bf16x8*)&Bpad[row][q * 8] = *(const bf16x8*)&Bw[(size_t)(bn + row) * ldb + k0 + q * 8];
        }
        __syncthreads();
#pragma unroll
        for (int ks = 0; ks < 2; ++ks) {
            bf16x8 a8 = *(const bf16x8*)&Apad[w * 16 + (l & 15)][ks * 32 + (l >> 4) * 8];
#pragma unroll
            for (int nf = 0; nf < 4; ++nf) {
                bf16x8 b8 = *(const bf16x8*)&Bpad[nf * 16 + (l & 15)][ks * 32 + (l >> 4) * 8];
                acc[nf] = __builtin_amdgcn_mfma_f32_16x16x32_bf16(a8, b8, acc[nf], 0, 0, 0);
            }
        }
        __syncthreads();
    }

    int rbase = bm + w * 16 + (l >> 4) * 4;
    int cl = l & 15;
#pragma unroll
    for (int nf = 0; nf < 4; ++nf) {
        int col = bn + nf * 16 + cl;
#pragma unroll
        for (int j = 0; j < 4; ++j) {
            int row = rbase + j;
            if (col < N) {
                int orow = (row & 63) * T_ + (row >> 6);  // t*64+b -> b*T+t
                outF[(size_t)orow * ldo + col] = acc[nf][j] + bias[col];
            }
        }
    }
}

// ===========================================================================
// STEP KERNEL 1 — per-batch (64 blocks x 512 thr, no cross-block deps):
//  hw-reduce: 1 gate/thread (coalesced, 32 adds)
//  scores over 8 waves (7 iters/wave); softmax (redundant per-thread)
//  g1pre SPLIT-P: half h=tid>>8 sums p-rows [0,25)/[25,49) into gsum[h][]
//    (halves the 49-row serial chain; bf16x8 loads kept — r11 lesson)
//  pw1: 1 gate-col/thread
// ===========================================================================
__global__ __launch_bounds__(512) void attn1_k(
    const float* __restrict__ hwp, const float* __restrict__ b2,
    const bf16_t* __restrict__ fW1b, const float* __restrict__ V,
    const float* __restrict__ bV, const bf16_t* __restrict__ F1g,
    const bf16_t* __restrict__ xeb, const float* __restrict__ G1h,
    const float* __restrict__ c1r, float* __restrict__ c1w,
    bf16_t* __restrict__ h1w)
{
    const int b = blockIdx.x, tid = threadIdx.x;
    const int w = tid >> 6, l = tid & 63;
    __shared__ float hw[512];
    __shared__ float sc[64];
    __shared__ float wn[64];
    __shared__ float gsum[2][2048];

    {   // hw reduce over 32 partials (contiguous [b][nb][a] layout)
        float a0 = b2[tid];
        const float* hp = hwp + (size_t)b * 16384 + tid;
#pragma unroll 8
        for (int nb = 0; nb < 32; ++nb) a0 += hp[nb * 512];
        hw[tid] = a0;
    }
    __syncthreads();
    {   // scores (8 waves)
        float hwr[8], Vr[8];
#pragma unroll
        for (int i = 0; i < 8; ++i) { hwr[i] = hw[l * 8 + i]; Vr[i] = V[l * 8 + i]; }
        for (int pq = w; pq < P_; pq += 8) {
            bf16x8 f8 = *(const bf16x8*)&fW1b[(size_t)(b * P_ + pq) * 512 + l * 8];
            float s = 0.f;
#pragma unroll
            for (int i = 0; i < 8; ++i) s += tanhf((float)f8[i] + hwr[i]) * Vr[i];
#pragma unroll
            for (int o = 32; o; o >>= 1) s += __shfl_xor(s, o);
            if (l == 0) sc[pq] = s + bV[0];
        }
    }
    __syncthreads();
    {   // softmax
        float m = -1e30f;
        for (int q = 0; q < P_; ++q) m = fmaxf(m, sc[q]);
        float ss = 0.f;
        for (int q = 0; q < P_; ++q) ss += expf(sc[q] - m);
        if (tid < P_) wn[tid] = expf(sc[tid] - m) / ss;
    }
    __syncthreads();
    {   // g1pre split-P: half h covers rows [h*25, h*25+pn)
        const int h = tid >> 8, th = tid & 255;
        const int p0 = h ? 25 : 0, pn = h ? 24 : 25;
        float acc[8] = {};
        const bf16_t* fg = F1g + ((size_t)b * P_ + p0) * 2048 + th * 8;
        for (int q = 0; q < pn; ++q) {
            bf16x8 f8 = *(const bf16x8*)&fg[(size_t)q * 2048];
            float wq = wn[p0 + q];
#pragma unroll
            for (int i = 0; i < 8; ++i) acc[i] += wq * (float)f8[i];
        }
#pragma unroll
        for (int i = 0; i < 8; ++i) gsum[h][th * 8 + i] = acc[i];
    }
    __syncthreads();
    {   // pw1: one gate-col per thread
        const int d = tid;
        const bf16_t* xb = xeb + (size_t)b * G4;
        const float* gh = G1h + b * 2048;
        float gi = (float)xb[d]        + gsum[0][d]        + gsum[1][d]        + gh[d];
        float gf = (float)xb[512 + d]  + gsum[0][512 + d]  + gsum[1][512 + d]  + gh[512 + d];
        float gg = (float)xb[1024 + d] + gsum[0][1024 + d] + gsum[1][1024 + d] + gh[1024 + d];
        float go = (float)xb[1536 + d] + gsum[0][1536 + d] + gsum[1][1536 + d] + gh[1536 + d];
        int idx = b * 512 + d;
        float cn = sigf(gf) * c1r[idx] + sigf(gi) * tanhf(gg);
        c1w[idx] = cn;
        h1w[idx] = (bf16_t)(sigf(go) * tanhf(cn));
    }
}

// ===========================================================================
// STEP KERNEL 2 — 64 blocks x 512 thr (verified r12, unchanged):
//  bid 0..31: gates2 8-wave K-split + LDS reduce -> pw2 -> h2(t+1) strip;
//    hwp tail (16 nt/wave, K=16-zero-padded MFMA vs W2sp, [b][nb][a]).
//  bid 32..63: G1h(t+1) strip, 8-wave K-split.
// ===========================================================================
__global__ __launch_bounds__(512) void gate2_k(
    const bf16_t* __restrict__ h1n, const bf16_t* __restrict__ h2r,
    const bf16_t* __restrict__ fp2, const bf16_t* __restrict__ fp1h,
    const bf16_t* __restrict__ W2sp, const float* __restrict__ bsum2,
    const float* __restrict__ c2r, float* __restrict__ c2w,
    bf16_t* __restrict__ h2w, float* __restrict__ G1h, float* __restrict__ hwp)
{
    const int bid = blockIdx.x, tid = threadIdx.x;
    const int w = tid >> 6, l = tid & 63;
    const int l15 = l & 15, koff = (l >> 4) * 8;
    const int mt = w & 3, kh = w >> 2;
    __shared__ float red[2][4][4][256];   // 32 KB
    __shared__ bf16_t h2t[64 * 16];       // 2 KB

    if (bid < 32) {
        const int nb = bid;
        {
            const int arow = mt * 16 + l15;
            const bf16_t* ap = (kh == 0 ? h1n : h2r) + arow * 512 + koff;
            const bf16_t* wp = fp2 + ((size_t)nb * 32 + kh * 16) * 2048 + l * 8;
            f32x4 acc[4] = {};
#pragma unroll
            for (int kf = 0; kf < 16; ++kf) {
                bf16x8 a8 = *(const bf16x8*)&ap[kf * 32];
                const bf16_t* wk = wp + (size_t)kf * 2048;
#pragma unroll
                for (int s = 0; s < 4; ++s) {
                    bf16x8 w8 = *(const bf16x8*)&wk[s * 512];
                    acc[s] = __builtin_amdgcn_mfma_f32_16x16x32_bf16(a8, w8, acc[s], 0, 0, 0);
                }
            }
#pragma unroll
            for (int s = 0; s < 4; ++s) *(f32x4*)&red[kh][mt][s][l * 4] = acc[s];
        }
        __syncthreads();
        if (w < 4) {
            const int d = nb * 16 + l15;
            const int rb = w * 16 + ((l >> 4) << 2);
            f32x4 v[4];
#pragma unroll
            for (int s = 0; s < 4; ++s)
                v[s] = *(const f32x4*)&red[0][w][s][l * 4] + *(const f32x4*)&red[1][w][s][l * 4];
#pragma unroll
            for (int j = 0; j < 4; ++j) {
                int row = rb + j;
                float gi = v[0][j] + bsum2[d];
                float gf = v[1][j] + bsum2[512 + d];
                float gg = v[2][j] + bsum2[1024 + d];
                float go = v[3][j] + bsum2[1536 + d];
                float cn = sigf(gf) * c2r[row * 512 + d] + sigf(gi) * tanhf(gg);
                c2w[row * 512 + d] = cn;
                bf16_t hb = (bf16_t)(sigf(go) * tanhf(cn));
                h2w[row * 512 + d] = hb;
                h2t[row * 16 + l15] = hb;
            }
        }
        __syncthreads();
        {
            bf16x8 a8 = {};
            if ((l >> 4) < 2) a8 = *(const bf16x8*)&h2t[(mt * 16 + l15) * 16 + koff];
            const int row0 = mt * 16 + (l >> 4) * 4;
            for (int q = 0; q < 16; ++q) {
                int nt = kh * 16 + q;
                bf16x8 b8 = *(const bf16x8*)&W2sp[((size_t)(nb * 32 + nt) * 64 + l) * 8];
                f32x4 acc2 = {};
                acc2 = __builtin_amdgcn_mfma_f32_16x16x32_bf16(a8, b8, acc2, 0, 0, 0);
                const int col = nt * 16 + l15;
#pragma unroll
                for (int j = 0; j < 4; ++j)
                    hwp[(size_t)(row0 + j) * 16384 + nb * 512 + col] = acc2[j];
            }
        }
    } else {
        const int nb = bid - 32;
        {
            const int arow = mt * 16 + l15;
            const bf16_t* ap = h1n + arow * 512 + kh * 256 + koff;
            const bf16_t* wp = fp1h + ((size_t)nb * 16 + kh * 8) * 2048 + l * 8;
            f32x4 acc[4] = {};
#pragma unroll
            for (int kf = 0; kf < 8; ++kf) {
                bf16x8 a8 = *(const bf16x8*)&ap[kf * 32];
                const bf16_t* wk = wp + (size_t)kf * 2048;
#pragma unroll
                for (int s = 0; s < 4; ++s) {
                    bf16x8 w8 = *(const bf16x8*)&wk[s * 512];
                    acc[s] = __builtin_amdgcn_mfma_f32_16x16x32_bf16(a8, w8, acc[s], 0, 0, 0);
                }
            }
#pragma unroll
            for (int s = 0; s < 4; ++s) *(f32x4*)&red[kh][mt][s][l * 4] = acc[s];
        }
        __syncthreads();
        if (w < 4) {
            const int d = nb * 16 + l15;
            const int rb = w * 16 + ((l >> 4) << 2);
#pragma unroll
            for (int s = 0; s < 4; ++s) {
                f32x4 v = *(const f32x4*)&red[0][w][s][l * 4] + *(const f32x4*)&red[1][w][s][l * 4];
#pragma unroll
                for (int j = 0; j < 4; ++j)
                    G1h[(rb + j) * 2048 + s * 512 + d] = v[j];
            }
        }
    }
}

// ---------------------------------------------------------------------------
extern "C" void kernel_launch(void* const* d_in, const int* in_sizes, int n_in,
                              void* d_out, int out_size, void* d_ws, size_t ws_size,
                              hipStream_t stream)
{
    const float* features = (const float*)d_in[0];
    const int*   captions = (const int*)d_in[1];
    const float* emb   = (const float*)d_in[2];
    const float* W1    = (const float*)d_in[3];
    const float* b1    = (const float*)d_in[4];
    const float* W2    = (const float*)d_in[5];
    const float* b2    = (const float*)d_in[6];
    const float* V     = (const float*)d_in[7];
    const float* bV    = (const float*)d_in[8];
    const float* W_ih1 = (const float*)d_in[9];
    const float* W_hh1 = (const float*)d_in[10];
    const float* b_ih1 = (const float*)d_in[11];
    const float* b_hh1 = (const float*)d_in[12];
    const float* W_ih2 = (const float*)d_in[13];
    const float* W_hh2 = (const float*)d_in[14];
    const float* b_ih2 = (const float*)d_in[15];
    const float* b_hh2 = (const float*)d_in[16];
    const float* fc_W  = (const float*)d_in[17];
    const float* fc_b  = (const float*)d_in[18];
    float* out = (float*)d_out;

    char* ws = (char*)d_ws;
    size_t off = 0;
    auto alloc = [&](size_t nbytes) {
        char* pp = ws + off;
        off = (off + nbytes + 255) & ~(size_t)255;
        return pp;
    };
    bf16_t* fW1b   = (bf16_t*)alloc(3136L * 512 * 2);    // 3.2 MB
    bf16_t* F1g    = (bf16_t*)alloc(3136L * 2048 * 2);   // 12.8 MB
    bf16_t* W2sp   = (bf16_t*)alloc(32L * 32 * 64 * 8 * 2); // 1.0 MB
    bf16_t* fp1h   = (bf16_t*)alloc(32L * 16 * 2048 * 2);   // 2.1 MB
    bf16_t* fp2    = (bf16_t*)alloc(2048L * 1024 * 2);   // 4.2 MB
    bf16_t* fcWb   = (bf16_t*)alloc((size_t)VPAD * 512 * 2); // 10.5 MB
    bf16_t* xgb    = (bf16_t*)alloc(1920L * 256 * 2);
    bf16_t* xembb  = (bf16_t*)alloc(1920L * 2048 * 2);   // 7.9 MB
    float*  bsum1  = (float*)alloc(2048 * 4);
    float*  bsum2  = (float*)alloc(2048 * 4);
    float*  hwp    = (float*)alloc(32L * SL * 4);        // 4.0 MB, [b][nb][a]
    float*  G1h    = (float*)alloc(64L * 2048 * 4);      // 0.5 MB
    bf16_t* h1s    = (bf16_t*)alloc((size_t)(T_ + 1) * SL * 2);
    bf16_t* h2s    = (bf16_t*)alloc((size_t)(T_ + 1) * SL * 2);
    float*  c1s    = (float*)alloc(2L * SL * 4);
    float*  c2s    = (float*)alloc(2L * SL * 4);
    // total ~51 MB (< proven 68.5 MB)

    prep_k<<<4096, 256, 0, stream>>>(
        b_ih1, b_hh1, bsum1, b_ih2, b_hh2, bsum2,
        W2, W2sp, W_hh1, fp1h, W_ih2, W_hh2, fp2, fc_W, fcWb,
        captions, emb, xgb,
        h1s, h2s, c1s, c2s, hwp, G1h);

    // fused: fW1b / xembb / F1g in one node
    mm3_k<<<2920, 256, 0, stream>>>(
        features, xgb, W1, W_ih1, b1, bsum1, fW1b, xembb, F1g);

    for (int t = 0; t < T_; ++t) {
        attn1_k<<<B_, 512, 0, stream>>>(
            hwp, b2, fW1b, V, bV, F1g,
            xembb + (size_t)t * B_ * G4, G1h,
            c1s + (size_t)(t & 1) * SL, c1s + (size_t)((t + 1) & 1) * SL,
            h1s + (size_t)(t + 1) * SL);
        gate2_k<<<64, 512, 0, stream>>>(
            h1s + (size_t)(t + 1) * SL, h2s + (size_t)t * SL,
            fp2, fp1h, W2sp, bsum2,
            c2s + (size_t)(t & 1) * SL, c2s + (size_t)((t + 1) & 1) * SL,
            h2s + (size_t)(t + 1) * SL, G1h, hwp);
    }

    // out = h2(1..30) @ fc_W^T + fc_b  (f32 out, row remap t*64+b -> b*T+t)
    mm_fc<<<dim3(VPAD / 64, (T_ * B_) / 64), 256, 0, stream>>>(
        h2s + SL, DEC, fcWb, DEC, fc_b, out, VOCAB, VOCAB, DEC);
}